// Round 9
// baseline (190.020 us; speedup 1.0000x reference)
//
#include <hip/hip_runtime.h>
#include <hip/hip_bf16.h>
#include <math.h>

#define NN 768
#define FF 128
#define VV 64
#define RH 16
#define NPLANES 12              // partial planes (after in-block reduce)
#define SUB_SENDERS 16          // senders per kc-sub (48 subs total)
#define SUB_KSTEPS 8            // ksteps per kc-sub
#define KSTEPS 384              // 12288 / 32
#define NT_S 8                  // scalar n-tiles (128/16)
#define NT_V 16                 // vector n-tiles (256/16)

typedef __attribute__((ext_vector_type(8))) short bf16x8_t;
typedef __attribute__((ext_vector_type(4))) float f32x4;

__device__ __forceinline__ float silu_f(float a) {
  return a * __builtin_amdgcn_rcpf(1.0f + __expf(-a));
}

__device__ __forceinline__ short f2bf(float f) {
  __hip_bfloat16 h = __float2bfloat16(f);   // RNE; compiler pairs into v_cvt_pk_bf16_f32
  return __builtin_bit_cast(short, h);
}

// ---------------------------------------------------------------------------
// init: hs[n] = embed row; hsv[n] = embed @ Wsv[0]; hv = 0
// ---------------------------------------------------------------------------
__global__ __launch_bounds__(192) void init_kernel(
    const float* __restrict__ embed, const float* __restrict__ Wsv0,
    float* __restrict__ hs, float* __restrict__ hsv, float* __restrict__ hv)
{
  const int n = blockIdx.x, t = threadIdx.x;
  hv[n * 192 + t] = 0.0f;
  if (t < FF) hs[n * FF + t] = embed[t];
  if (t < VV) {
    float acc = 0.f;
    #pragma unroll 8
    for (int f = 0; f < FF; ++f) acc += embed[f] * Wsv0[f * VV + t];
    hsv[n * VV + t] = acc;
  }
}

// ---------------------------------------------------------------------------
// prep: build B matrices in MFMA-fragment-major layout (bf16).
// K index k = s*16 + h; 16x16x32 B-fragment: lane holds 8 contiguous k.
//   Bs[k][f]        = hs[s][f]  * Wr2s[h][f] / 64                 (N=128)
//   Bv[k][d*64+v]   = x[s][d]   * hsv[s][v] * Wr2v[h][v] / 64     (N=192)
//   Bv[k][192+v]    =             hsv[s][v] * Wr2v[h][v] / 64     (N=64)
// ---------------------------------------------------------------------------
__global__ __launch_bounds__(256) void prep_kernel(
    const float* __restrict__ hs, const float* __restrict__ hsv,
    const float* __restrict__ x,
    const float* __restrict__ Wr2s,   // [16][128] layer slice
    const float* __restrict__ Wr2v,   // [16][64]  layer slice
    unsigned short* __restrict__ Bs, unsigned short* __restrict__ Bv)
{
  const int gid   = blockIdx.x * 256 + threadIdx.x;
  const int lane  = gid & 63;
  const int tmp   = gid >> 6;
  const int ntile = tmp % 24;
  const int kstep = tmp / 24;
  if (kstep >= KSTEPS) return;
  const int qq = lane >> 4;              // octet index 0..3
  const int s  = kstep * 2 + (qq >> 1);
  const int hb = (qq & 1) * 8;

  bf16x8_t o;
  if (ntile < NT_S) {
    const int f = ntile * 16 + (lane & 15);
    const float hf = hs[s * FF + f] * 0.015625f;
    #pragma unroll
    for (int e = 0; e < 8; ++e)
      o[e] = f2bf(hf * Wr2s[(hb + e) * FF + f]);
    *(bf16x8_t*)&Bs[((size_t)(kstep * NT_S + ntile) * 64 + lane) * 8] = o;
  } else {
    const int nt2 = ntile - NT_S;
    const int n   = nt2 * 16 + (lane & 15);
    int v; float scale;
    if (n < 192) { const int dd = n >> 6; v = n & 63;
                   scale = x[s * 3 + dd] * hsv[s * VV + v] * 0.015625f; }
    else         { v = n - 192; scale = hsv[s * VV + v] * 0.015625f; }
    #pragma unroll
    for (int e = 0; e < 8; ++e)
      o[e] = f2bf(scale * Wr2v[(hb + e) * VV + v]);
    *(bf16x8_t*)&Bv[((size_t)(kstep * NT_V + nt2) * 64 + lane) * 8] = o;
  }
}

// ---------------------------------------------------------------------------
// edge GEMM v6: 2 kinds. Wave = 1 mtile (16 rows) x FULL N of its kind
// (scalar: 8 ntiles of Ps; vector: 16 ntiles of Pv) -> each A fragment is
// computed exactly ONCE per variant. A in registers (lane q=lane>>4 holds
// k=q*8+e: s=2 per kstep via q>>1, h-half via q&1 -> 8 silu per lane/kstep).
// Block = 4 waves, same (kind, rowblock), consecutive kc-subs; K-loop has
// NO LDS and NO barriers; at the end the 4 waves LDS-reduce their partials
// (chunked, 2 barriers/chunk) and write ONE plane -> NPLANES=12 stays small
// while wave count = 4608 (4.5/SIMD). Partials per plane, no atomics.
// ---------------------------------------------------------------------------
__global__ __launch_bounds__(256) void edge_gemm(
    const float* __restrict__ x,
    const unsigned short* __restrict__ Bs,
    const unsigned short* __restrict__ Bv,
    const float* __restrict__ Wr1,    // [16] layer slice
    float* __restrict__ Ps,           // [NPLANES][768][128]
    float* __restrict__ Pv)           // [NPLANES][768][256]
{
  __shared__ f32x4 Rsh[4][64][4];     // 16 KB epilogue-reduce scratch

  // bijective XCD swizzle: xcd = b&7 gets groups g = xcd*3 + {0,1,2};
  // kind interleaved (g&1) so each XCD mixes scalar/vector work.
  const int b    = blockIdx.x;
  const int hi   = b >> 3;            // 0..143
  const int gi   = hi / 48;           // 0..2
  const int rb   = hi - gi * 48;      // 0..47 rowblock (16 rows)
  const int g    = (b & 7) * 3 + gi;  // 0..23
  const int kind = g & 1;             // 0 scalar, 1 vector
  const int kcg  = g >> 1;            // 0..11 plane

  const int tid  = threadIdx.x;
  const int w    = tid >> 6;          // wave = kc-sub within group
  const int lane = tid & 63;
  const int q    = lane >> 4;
  const int ssel = q >> 1;            // which of 2 senders in a kstep
  const int hb   = (q & 1) << 3;      // h-half

  const unsigned short* __restrict__ Bbase = kind ? Bv : Bs;
  const int NT = kind ? NT_V : NT_S;

  float wr1[8];
  #pragma unroll
  for (int e = 0; e < 8; ++e) wr1[e] = Wr1[hb + e];

  const int r = rb * 16 + (lane & 15);
  const float xr0 = x[r * 3 + 0], xr1 = x[r * 3 + 1], xr2 = x[r * 3 + 2];

  const int kcsub = kcg * 4 + w;            // 0..47
  const int sbase = kcsub * SUB_SENDERS;

  f32x4 acc[16];
  #pragma unroll
  for (int i = 0; i < 16; ++i) acc[i] = (f32x4){0.f, 0.f, 0.f, 0.f};

  #pragma unroll 2
  for (int ks = 0; ks < SUB_KSTEPS; ++ks) {
    const int s = sbase + ks * 2 + ssel;
    const float vx = x[s * 3 + 0] - xr0;
    const float vy = x[s * 3 + 1] - xr1;
    const float vz = x[s * 3 + 2] - xr2;
    const float dd = __builtin_amdgcn_sqrtf(vx * vx + vy * vy + vz * vz);
    const float pre = kind ? __builtin_amdgcn_rcpf(dd + 1e-8f) : 1.0f;
    bf16x8_t a;
    #pragma unroll
    for (int e = 0; e < 8; ++e) a[e] = f2bf(silu_f(dd * wr1[e]) * pre);

    const int kgb = kcsub * SUB_KSTEPS + ks;
    const unsigned short* bp = &Bbase[((size_t)(kgb * NT) * 64 + lane) * 8];
    if (kind == 0) {
      #pragma unroll
      for (int n = 0; n < NT_S; ++n) {
        const bf16x8_t bb = *(const bf16x8_t*)&bp[(size_t)n * 512];
        acc[n] = __builtin_amdgcn_mfma_f32_16x16x32_bf16(a, bb, acc[n], 0, 0, 0);
      }
    } else {
      #pragma unroll
      for (int n = 0; n < NT_V; ++n) {
        const bf16x8_t bb = *(const bf16x8_t*)&bp[(size_t)n * 512];
        acc[n] = __builtin_amdgcn_mfma_f32_16x16x32_bf16(a, bb, acc[n], 0, 0, 0);
      }
    }
  }

  // ---- epilogue: 4-wave LDS reduce over kc-subs, chunked by 4 ntiles ----
  const int chunks = NT >> 2;
  const int rowb = rb * 16 + ((lane >> 4) << 2);   // + reg
  for (int c = 0; c < chunks; ++c) {
    #pragma unroll
    for (int i = 0; i < 4; ++i) Rsh[w][lane][i] = acc[c * 4 + i];
    __syncthreads();
    {
      const int n = c * 4 + w;                      // each wave owns 1 ntile
      const f32x4 v0 = Rsh[0][lane][w];
      const f32x4 v1 = Rsh[1][lane][w];
      const f32x4 v2 = Rsh[2][lane][w];
      const f32x4 v3 = Rsh[3][lane][w];
      const int col = n * 16 + (lane & 15);
      #pragma unroll
      for (int reg = 0; reg < 4; ++reg) {
        const float val = v0[reg] + v1[reg] + v2[reg] + v3[reg];
        const int row = rowb + reg;
        if (kind == 0)
          Ps[((size_t)kcg * NN + row) * FF + col] = val;
        else
          Pv[((size_t)kcg * NN + row) * 256 + col] = val;
      }
    }
    __syncthreads();
  }
}

// ---------------------------------------------------------------------------
// reduce splitK partials, fully coalesced float4 loads, 12-deep ILP.
// ---------------------------------------------------------------------------
#define ES4 (NN * FF / 4)     // 24576
#define EV4 (NN * 256 / 4)    // 49152
__global__ __launch_bounds__(256) void reduce_kernel(
    const float* __restrict__ Ps, const float* __restrict__ Pv,
    float* __restrict__ aggs, float* __restrict__ pvsum)
{
  const int gid = blockIdx.x * 256 + threadIdx.x;
  if (gid < ES4) {
    const f32x4* p = (const f32x4*)Ps + gid;
    f32x4 a = (f32x4){0.f, 0.f, 0.f, 0.f};
    #pragma unroll
    for (int kc = 0; kc < NPLANES; ++kc) {
      const f32x4 v = p[(size_t)kc * ES4];
      a.x += v.x; a.y += v.y; a.z += v.z; a.w += v.w;
    }
    ((f32x4*)aggs)[gid] = a;
  } else {
    const int g2 = gid - ES4;
    const f32x4* p = (const f32x4*)Pv + g2;
    f32x4 a = (f32x4){0.f, 0.f, 0.f, 0.f};
    #pragma unroll
    for (int kc = 0; kc < NPLANES; ++kc) {
      const f32x4 v = p[(size_t)kc * EV4];
      a.x += v.x; a.y += v.y; a.z += v.z; a.w += v.w;
    }
    ((f32x4*)pvsum)[g2] = a;
  }
}

// ---------------------------------------------------------------------------
// node update (512 threads, 4-way K-split GEMVs):
//   av = C1 - x*C2; inv = |av|^2;
//   hs = silu(hs + aggs@Wss + inv@Wvs); hv += av@Wvv; hsv = hs_new@Wsv_next
// ---------------------------------------------------------------------------
__global__ __launch_bounds__(512) void node_kernel(
    const float* __restrict__ aggs,     // [768][128]
    const float* __restrict__ pvsum,    // [768][256]
    const float* __restrict__ x,
    const float* __restrict__ Wss,
    const float* __restrict__ Wvs,
    const float* __restrict__ Wvv,
    const float* __restrict__ Wsv_next,
    float* __restrict__ hs,
    float* __restrict__ hsv,
    float* __restrict__ hv,
    int has_next)
{
  __shared__ float as_l[FF];
  __shared__ float pvs_l[256];
  __shared__ float av_l[192];
  __shared__ float inv_l[VV];
  __shared__ float hsn[FF];
  __shared__ float red[512];
  __shared__ float red2[384];
  const int n = blockIdx.x, t = threadIdx.x;

  if (t < FF) as_l[t] = aggs[n * FF + t];
  if (t >= 128 && t < 384) pvs_l[t - 128] = pvsum[n * 256 + (t - 128)];
  __syncthreads();

  if (t < VV) {
    const float base = pvs_l[192 + t];
    const float a0 = pvs_l[t]       - x[n * 3 + 0] * base;
    const float a1 = pvs_l[64 + t]  - x[n * 3 + 1] * base;
    const float a2 = pvs_l[128 + t] - x[n * 3 + 2] * base;
    av_l[t * 3 + 0] = a0; av_l[t * 3 + 1] = a1; av_l[t * 3 + 2] = a2;
    inv_l[t] = a0 * a0 + a1 * a1 + a2 * a2;
  }
  __syncthreads();

  // hs partials: 4-way split over K
  {
    const int f = t & 127, part = t >> 7;
    float acc = 0.f;
    const float* wp = Wss + (part * 32) * FF + f;
    #pragma unroll 8
    for (int kk = 0; kk < 32; ++kk) acc += as_l[part * 32 + kk] * wp[kk * FF];
    const float* vp = Wvs + (part * 16) * FF + f;
    #pragma unroll 8
    for (int vv = 0; vv < 16; ++vv) acc += inv_l[part * 16 + vv] * vp[vv * FF];
    red[part * 128 + f] = acc;
  }
  __syncthreads();

  // hs finalize || hv partials (2-way split over v)
  if (t < FF) {
    const float hnew =
        silu_f(hs[n * FF + t] + red[t] + red[128 + t] + red[256 + t] + red[384 + t]);
    hs[n * FF + t] = hnew;
    hsn[t] = hnew;
  }
  if (t < 384) {
    const int part = t / 192, j = t - part * 192;
    const int wv = j / 3, d = j - wv * 3;
    float acc = 0.f;
    const float* vp = Wvv + (part * 32) * VV + wv;
    #pragma unroll 8
    for (int v = 0; v < 32; ++v) acc += av_l[(part * 32 + v) * 3 + d] * vp[v * VV];
    red2[part * 192 + j] = acc;
  }
  __syncthreads();

  // hv finalize || hsv partials (4-way split over f)
  if (t < 192) hv[n * 192 + t] += red2[t] + red2[192 + t];
  if (has_next) {
    if (t < 256) {
      const int v = t & 63, part = t >> 6;
      float acc = 0.f;
      const float* wp = Wsv_next + (part * 32) * VV + v;
      #pragma unroll 8
      for (int f = 0; f < 32; ++f) acc += hsn[part * 32 + f] * wp[f * VV];
      red[t] = acc;
    }
    __syncthreads();
    if (t < VV) hsv[n * VV + t] = red[t] + red[64 + t] + red[128 + t] + red[192 + t];
  }
}

// ---------------------------------------------------------------------------
// readout (512 threads, K-split GEMVs)
// ---------------------------------------------------------------------------
__global__ __launch_bounds__(512) void readout_kernel(
    const float* __restrict__ hs,
    const float* __restrict__ hv,
    const float* __restrict__ Wro_s1,
    const float* __restrict__ Wro_s2,
    const float* __restrict__ Wro_v1,
    const float* __restrict__ Wro_v2,
    float* __restrict__ out)
{
  __shared__ float hs_l[FF];
  __shared__ float hv_l[192];
  __shared__ float t1[FF];
  __shared__ float tv1[192];
  __shared__ float redA[512];
  __shared__ float redB[384];
  const int n = blockIdx.x, t = threadIdx.x;
  if (t < FF) hs_l[t] = hs[n * FF + t];
  if (t >= 128 && t < 320) hv_l[t - 128] = hv[n * 192 + (t - 128)];
  __syncthreads();

  // t1 partials
  {
    const int f = t & 127, part = t >> 7;
    float acc = 0.f;
    const float* wp = Wro_s1 + (part * 32) * FF + f;
    #pragma unroll 8
    for (int kk = 0; kk < 32; ++kk) acc += hs_l[part * 32 + kk] * wp[kk * FF];
    redA[part * 128 + f] = acc;
  }
  __syncthreads();
  if (t < FF) t1[t] = silu_f(redA[t] + redA[128 + t] + redA[256 + t] + redA[384 + t]);
  if (t < 384) {  // tv1 partials (2-way over v)
    const int part = t / 192, j = t - part * 192;
    const int wv = j / 3, d = j - wv * 3;
    float acc = 0.f;
    const float* vp = Wro_v1 + (part * 32) * VV + wv;
    #pragma unroll 8
    for (int v = 0; v < 32; ++v) acc += hv_l[(part * 32 + v) * 3 + d] * vp[v * VV];
    redB[part * 192 + j] = acc;
  }
  __syncthreads();
  if (t < 192) tv1[t] = redB[t] + redB[192 + t];
  if (t < 256) {  // out_s partials (4-way over f)
    const int o = t & 63, part = t >> 6;
    float acc = 0.f;
    const float* wp = Wro_s2 + (part * 32) * 64 + o;
    #pragma unroll 8
    for (int f = 0; f < 32; ++f) acc += t1[part * 32 + f] * wp[f * 64];
    redA[t] = acc;
  }
  __syncthreads();
  if (t < 64) out[n * 160 + t] = redA[t] + redA[64 + t] + redA[128 + t] + redA[192 + t];
  if (t < 192) {  // out_v partials (2-way over w)
    const int part = t / 96, j = t - part * 96;
    const int w2 = j / 3, d = j - w2 * 3;
    float acc = 0.f;
    const float* vp = Wro_v2 + (part * 32) * 32 + w2;
    #pragma unroll 8
    for (int wv = 0; wv < 32; ++wv) acc += tv1[(part * 32 + wv) * 3 + d] * vp[wv * 32];
    redB[part * 96 + j] = acc;
  }
  __syncthreads();
  if (t < 96) out[n * 160 + 64 + t] = redB[t] + redB[96 + t];
}

// ---------------------------------------------------------------------------
extern "C" void kernel_launch(void* const* d_in, const int* in_sizes, int n_in,
                              void* d_out, int out_size, void* d_ws, size_t ws_size,
                              hipStream_t stream) {
  const float* x      = (const float*)d_in[0];
  const float* embed  = (const float*)d_in[3];
  const float* Wr1    = (const float*)d_in[4];   // [2][1][16]
  const float* Wr2s   = (const float*)d_in[5];   // [2][16][128]
  const float* Wr2v   = (const float*)d_in[6];   // [2][16][64]
  const float* Wsv    = (const float*)d_in[7];   // [2][128][64]
  const float* Wss    = (const float*)d_in[8];   // [2][128][128]
  const float* Wvs    = (const float*)d_in[9];   // [2][64][128]
  const float* Wvv    = (const float*)d_in[10];  // [2][64][64]
  const float* Wro_s1 = (const float*)d_in[11];
  const float* Wro_s2 = (const float*)d_in[12];
  const float* Wro_v1 = (const float*)d_in[13];
  const float* Wro_v2 = (const float*)d_in[14];

  float* ws_f = (float*)d_ws;
  float* hs    = ws_f;                      // 768*128
  float* hsv   = hs + NN * FF;              // 768*64
  float* hv    = hsv + NN * VV;             // 768*192
  float* aggs  = hv + NN * 192;             // 768*128
  float* pvsum = aggs + NN * FF;            // 768*256
  float* Ps    = pvsum + NN * 256;          // 12*768*128
  float* Pv    = Ps + (size_t)NPLANES * NN * FF;   // 12*768*256
  unsigned short* Bs = (unsigned short*)(Pv + (size_t)NPLANES * NN * 256);
  unsigned short* Bv = Bs + (size_t)12288 * 128;
  float* out = (float*)d_out;

  init_kernel<<<NN, 192, 0, stream>>>(embed, Wsv, hs, hsv, hv);

  for (int l = 0; l < 2; ++l) {
    prep_kernel<<<2304, 256, 0, stream>>>(
        hs, hsv, x, Wr2s + l * RH * FF, Wr2v + l * RH * VV, Bs, Bv);
    edge_gemm<<<1152, 256, 0, stream>>>(
        x, Bs, Bv, Wr1 + l * RH, Ps, Pv);
    reduce_kernel<<<(ES4 + EV4) / 256, 256, 0, stream>>>(Ps, Pv, aggs, pvsum);
    node_kernel<<<NN, 512, 0, stream>>>(
        aggs, pvsum, x, Wss + l * FF * FF, Wvs + l * VV * FF, Wvv + l * VV * VV,
        Wsv + ((l + 1) < 2 ? (l + 1) * FF * VV : 0), hs, hsv, hv,
        (l + 1) < 2 ? 1 : 0);
  }

  readout_kernel<<<NN, 512, 0, stream>>>(hs, hv, Wro_s1, Wro_s2, Wro_v1,
                                         Wro_v2, out);
}

// Round 10
// 78.694 us; speedup vs baseline: 2.4147x; 2.4147x over previous
//
#include <hip/hip_runtime.h>
#include <hip/hip_bf16.h>
#include <math.h>

#define NN 768
#define FF 128
#define VV 64
#define RH 16
#define SPLITK 24
#define SEND_PER_KC 32          // 768 / SPLITK
#define NITER 4                 // SEND_PER_KC / 8 senders per iter
#define KSTEPS 384              // 12288 / 32
#define NT_S 8                  // scalar n-tiles (128/16)
#define NT_V 16                 // vector n-tiles (256/16)
#define MB_N 24                 // M-blocks (768/32)
#define CHUNK 256

typedef __attribute__((ext_vector_type(8))) short bf16x8_t;
typedef __attribute__((ext_vector_type(4))) float f32x4;

__device__ __forceinline__ float silu_f(float a) {
  // a * rcp(1+exp(-a)) : ~1ulp vs precise div; absmax headroom is 4.5x
  return a * __builtin_amdgcn_rcpf(1.0f + __expf(-a));
}

__device__ __forceinline__ short f2bf(float f) {
  __hip_bfloat16 h = __float2bfloat16(f);  // RNE; pairs into v_cvt_pk_bf16_f32
  return __builtin_bit_cast(short, h);
}

// ---------------------------------------------------------------------------
// init: hs[n] = embed row; hsv[n] = embed @ Wsv[0]; hv = 0
// ---------------------------------------------------------------------------
__global__ __launch_bounds__(192) void init_kernel(
    const float* __restrict__ embed, const float* __restrict__ Wsv0,
    float* __restrict__ hs, float* __restrict__ hsv, float* __restrict__ hv)
{
  const int n = blockIdx.x, t = threadIdx.x;
  hv[n * 192 + t] = 0.0f;
  if (t < FF) hs[n * FF + t] = embed[t];
  if (t < VV) {
    float acc = 0.f;
    #pragma unroll 8
    for (int f = 0; f < FF; ++f) acc += embed[f] * Wsv0[f * VV + t];
    hsv[n * VV + t] = acc;
  }
}

// ---------------------------------------------------------------------------
// Layer-0 edge kernel (closed form; verified R2). hs == embed everywhere and
// hs_e @ Wsv == c[v] constant, so:
//   agg_s[r,f]   = embed[f]/64 * sum_h Wr2s[h,f] * R[r,h],  R[r,h]  = sum_s rf
//   agg_v[r,v,d] = c[v]/64     * sum_h Wr2v[h,v] * T[r,h,d], T[r,h,d]= sum_s rf*u_d
// ---------------------------------------------------------------------------
__global__ __launch_bounds__(256) void edge1_kernel(
    const float* __restrict__ x,
    const float* __restrict__ cvec,   // hsv row 0 == embed @ Wsv[0]
    const float* __restrict__ Wr1,    // [16]
    const float* __restrict__ Wr2s,   // [16][128]
    const float* __restrict__ Wr2v,   // [16][64]
    const float* __restrict__ embed,  // [128]
    float* __restrict__ agg_s,        // [N][128]
    float* __restrict__ agg_v)        // [N][64*3]
{
  __shared__ float x_s[NN * 3];
  __shared__ float rf_s[CHUNK * RH];
  __shared__ float u_s[CHUNK * 4];
  __shared__ float red[4][64];
  __shared__ float fin[64];

  const int r   = blockIdx.x;
  const int tid = threadIdx.x;
  const int j   = tid & 63;   // output index: h*4 + c
  const int q   = tid >> 6;   // sender quarter
  const int h   = j >> 2;
  const int c   = j & 3;
  const int sel = (c + 3) & 3;  // c==0 -> 3 (the 1.0 slot), else c-1

  for (int i = tid; i < NN * 3; i += 256) x_s[i] = x[i];

  float wr1[RH];
  #pragma unroll
  for (int hh = 0; hh < RH; ++hh) wr1[hh] = Wr1[hh];

  const float xr0 = x[r * 3 + 0], xr1 = x[r * 3 + 1], xr2 = x[r * 3 + 2];
  __syncthreads();

  float acc = 0.f;
  for (int cb = 0; cb < NN; cb += CHUNK) {
    {
      const int s = cb + tid;
      const float vx = x_s[s * 3 + 0] - xr0;
      const float vy = x_s[s * 3 + 1] - xr1;
      const float vz = x_s[s * 3 + 2] - xr2;
      const float d  = __builtin_amdgcn_sqrtf(vx * vx + vy * vy + vz * vz);
      const float iv = __builtin_amdgcn_rcpf(d + 1e-8f);
      *(float4*)&u_s[tid * 4] = make_float4(vx * iv, vy * iv, vz * iv, 1.0f);
      #pragma unroll
      for (int hh = 0; hh < RH; hh += 4) {
        float4 rv;
        rv.x = silu_f(d * wr1[hh + 0]);
        rv.y = silu_f(d * wr1[hh + 1]);
        rv.z = silu_f(d * wr1[hh + 2]);
        rv.w = silu_f(d * wr1[hh + 3]);
        *(float4*)&rf_s[tid * RH + hh] = rv;
      }
    }
    __syncthreads();

    const int base = q * 64;
    #pragma unroll 4
    for (int si = 0; si < 64; ++si) {
      const int sl = base + si;
      acc += rf_s[sl * RH + h] * u_s[sl * 4 + sel];
    }
    __syncthreads();
  }

  red[q][j] = acc;
  __syncthreads();
  if (tid < 64) fin[tid] = red[0][tid] + red[1][tid] + red[2][tid] + red[3][tid];
  __syncthreads();

  if (tid < FF) {
    float a = 0.f;
    #pragma unroll
    for (int hh = 0; hh < RH; ++hh) a += fin[hh * 4] * Wr2s[hh * FF + tid];
    agg_s[(size_t)r * FF + tid] = a * embed[tid] * (1.0f / 64.0f);
  }
  if (tid < 192) {
    const int v = tid / 3, d = tid - v * 3;
    float a = 0.f;
    #pragma unroll
    for (int hh = 0; hh < RH; ++hh) a += fin[hh * 4 + 1 + d] * Wr2v[hh * VV + v];
    agg_v[(size_t)r * 192 + tid] = a * cvec[v] * (1.0f / 64.0f);
  }
}

// ---------------------------------------------------------------------------
// prep: build B matrices in MFMA-fragment-major layout (bf16). (verified R3+)
//   Bs[k][f]        = hs[s][f]  * Wr2s[h][f] / 64                 (N=128)
//   Bv[k][d*64+v]   = x[s][d]   * hsv[s][v] * Wr2v[h][v] / 64     (N=192)
//   Bv[k][192+v]    =             hsv[s][v] * Wr2v[h][v] / 64     (N=64)
// ---------------------------------------------------------------------------
__global__ __launch_bounds__(256) void prep_kernel(
    const float* __restrict__ hs, const float* __restrict__ hsv,
    const float* __restrict__ x,
    const float* __restrict__ Wr2s,   // [16][128] layer slice
    const float* __restrict__ Wr2v,   // [16][64]  layer slice
    unsigned short* __restrict__ Bs, unsigned short* __restrict__ Bv)
{
  const int gid   = blockIdx.x * 256 + threadIdx.x;
  const int lane  = gid & 63;
  const int tmp   = gid >> 6;
  const int ntile = tmp % 24;
  const int kstep = tmp / 24;
  if (kstep >= KSTEPS) return;
  const int qq = lane >> 4;              // octet index 0..3
  const int s  = kstep * 2 + (qq >> 1);
  const int hb = (qq & 1) * 8;

  bf16x8_t o;
  if (ntile < NT_S) {
    const int f = ntile * 16 + (lane & 15);
    const float hf = hs[s * FF + f] * 0.015625f;
    #pragma unroll
    for (int e = 0; e < 8; ++e)
      o[e] = f2bf(hf * Wr2s[(hb + e) * FF + f]);
    *(bf16x8_t*)&Bs[((size_t)(kstep * NT_S + ntile) * 64 + lane) * 8] = o;
  } else {
    const int nt2 = ntile - NT_S;
    const int n   = nt2 * 16 + (lane & 15);
    int v; float scale;
    if (n < 192) { const int dd = n >> 6; v = n & 63;
                   scale = x[s * 3 + dd] * hsv[s * VV + v] * 0.015625f; }
    else         { v = n - 192; scale = hsv[s * VV + v] * 0.015625f; }
    #pragma unroll
    for (int e = 0; e < 8; ++e)
      o[e] = f2bf(scale * Wr2v[(hb + e) * VV + v]);
    *(bf16x8_t*)&Bv[((size_t)(kstep * NT_V + nt2) * 64 + lane) * 8] = o;
  }
}

// ---------------------------------------------------------------------------
// edge GEMM (R5 structure verbatim, cheap A-gen math): M=32/block, 4 waves,
// grid = 24 Mb x {scalar,vector} x SPLITK=24 = 1152 blocks, XCD-swizzled.
// ---------------------------------------------------------------------------
__global__ __launch_bounds__(256) void edge_gemm(
    const float* __restrict__ x,
    const unsigned short* __restrict__ Bs,
    const unsigned short* __restrict__ Bv,
    const float* __restrict__ Wr1,    // [16] layer slice
    float* __restrict__ Ps,           // [SPLITK][768][128]
    float* __restrict__ Pv)           // [SPLITK][768][256]
{
  __shared__ unsigned short A_lds[4 * 2 * 64 * 8];  // 8 KB: [ks][mt][lane][8]

  // bijective XCD swizzle: 1152 = 8 * 144
  const int wg  = ((blockIdx.x & 7) * 144) + (blockIdx.x >> 3);
  const int nt  = wg / 576;
  const int rem = wg - nt * 576;
  const int kc  = rem / MB_N;
  const int mb  = rem - kc * MB_N;

  const int tid  = threadIdx.x;
  const int lane = tid & 63;
  const int w    = tid >> 6;

  float wr1[RH];
  #pragma unroll
  for (int h = 0; h < RH; ++h) wr1[h] = Wr1[h];

  const int r_local = tid & 31;
  const int s_ii    = tid >> 5;        // 0..7
  const int r = mb * 32 + r_local;
  const int mt_w  = r_local >> 4;
  const int ks_w  = s_ii >> 1;
  const int lane0 = (r_local & 15) + ((s_ii & 1) << 5);

  const float xr0 = x[r * 3 + 0], xr1 = x[r * 3 + 1], xr2 = x[r * 3 + 2];
  float sx[NITER], sy[NITER], sz[NITER];
  #pragma unroll
  for (int it = 0; it < NITER; ++it) {
    const int s = kc * SEND_PER_KC + it * 8 + s_ii;
    sx[it] = x[s * 3 + 0]; sy[it] = x[s * 3 + 1]; sz[it] = x[s * 3 + 2];
  }

  f32x4 acc[8];
  #pragma unroll
  for (int i = 0; i < 8; ++i) acc[i] = (f32x4){0.f, 0.f, 0.f, 0.f};

  for (int it = 0; it < NITER; ++it) {
    // ---- A generation (registers only -> LDS), cheap-math chain ----
    {
      const float vx = sx[it] - xr0;
      const float vy = sy[it] - xr1;
      const float vz = sz[it] - xr2;
      const float dd = __builtin_amdgcn_sqrtf(vx * vx + vy * vy + vz * vz);
      const float mulf = nt ? __builtin_amdgcn_rcpf(dd + 1e-8f) : 1.0f;
      bf16x8_t o0, o1;
      #pragma unroll
      for (int h = 0; h < 8; ++h)
        o0[h] = f2bf(silu_f(dd * wr1[h]) * mulf);
      #pragma unroll
      for (int h = 8; h < 16; ++h)
        o1[h - 8] = f2bf(silu_f(dd * wr1[h]) * mulf);
      *(bf16x8_t*)&A_lds[((ks_w * 2 + mt_w) * 64 + lane0) * 8]      = o0;
      *(bf16x8_t*)&A_lds[((ks_w * 2 + mt_w) * 64 + lane0 + 16) * 8] = o1;
    }
    __syncthreads();

    // ---- MFMA ----
    const int kgb = kc * (SEND_PER_KC / 2) + it * 4;  // global kstep base
    if (nt == 0) {
      #pragma unroll
      for (int ks = 0; ks < 4; ++ks) {
        const bf16x8_t b0 =
            *(const bf16x8_t*)&Bs[((size_t)((kgb + ks) * NT_S + 2 * w) * 64 + lane) * 8];
        const bf16x8_t b1 =
            *(const bf16x8_t*)&Bs[((size_t)((kgb + ks) * NT_S + 2 * w + 1) * 64 + lane) * 8];
        #pragma unroll
        for (int mt = 0; mt < 2; ++mt) {
          const bf16x8_t a =
              *(const bf16x8_t*)&A_lds[((ks * 2 + mt) * 64 + lane) * 8];
          acc[mt * 2 + 0] = __builtin_amdgcn_mfma_f32_16x16x32_bf16(a, b0, acc[mt * 2 + 0], 0, 0, 0);
          acc[mt * 2 + 1] = __builtin_amdgcn_mfma_f32_16x16x32_bf16(a, b1, acc[mt * 2 + 1], 0, 0, 0);
        }
      }
    } else {
      #pragma unroll
      for (int ks = 0; ks < 4; ++ks) {
        bf16x8_t bv[4];
        #pragma unroll
        for (int j = 0; j < 4; ++j)
          bv[j] = *(const bf16x8_t*)&Bv[((size_t)((kgb + ks) * NT_V + 4 * w + j) * 64 + lane) * 8];
        #pragma unroll
        for (int mt = 0; mt < 2; ++mt) {
          const bf16x8_t a =
              *(const bf16x8_t*)&A_lds[((ks * 2 + mt) * 64 + lane) * 8];
          #pragma unroll
          for (int j = 0; j < 4; ++j)
            acc[mt * 4 + j] = __builtin_amdgcn_mfma_f32_16x16x32_bf16(a, bv[j], acc[mt * 4 + j], 0, 0, 0);
        }
      }
    }
    __syncthreads();
  }

  // ---- epilogue: write partials (each element written exactly once) ----
  const int rowq = (lane >> 4) << 2;     // D row = (lane>>4)*4 + reg
  if (nt == 0) {
    #pragma unroll
    for (int j = 0; j < 2; ++j) {
      const int col = (2 * w + j) * 16 + (lane & 15);
      #pragma unroll
      for (int mt = 0; mt < 2; ++mt) {
        #pragma unroll
        for (int reg = 0; reg < 4; ++reg) {
          const int row = mb * 32 + mt * 16 + rowq + reg;
          Ps[((size_t)kc * NN + row) * FF + col] = acc[mt * 2 + j][reg];
        }
      }
    }
  } else {
    #pragma unroll
    for (int j = 0; j < 4; ++j) {
      const int col = (4 * w + j) * 16 + (lane & 15);
      #pragma unroll
      for (int mt = 0; mt < 2; ++mt) {
        #pragma unroll
        for (int reg = 0; reg < 4; ++reg) {
          const int row = mb * 32 + mt * 16 + rowq + reg;
          Pv[((size_t)kc * NN + row) * 256 + col] = acc[mt * 4 + j][reg];
        }
      }
    }
  }
}

// ---------------------------------------------------------------------------
// reduce splitK partials, fully coalesced float4 loads, 24-deep ILP.
// ---------------------------------------------------------------------------
#define ES4 (NN * FF / 4)     // 24576
#define EV4 (NN * 256 / 4)    // 49152
__global__ __launch_bounds__(256) void reduce_kernel(
    const float* __restrict__ Ps, const float* __restrict__ Pv,
    float* __restrict__ aggs, float* __restrict__ pvsum)
{
  const int gid = blockIdx.x * 256 + threadIdx.x;
  if (gid < ES4) {
    const f32x4* p = (const f32x4*)Ps + gid;
    f32x4 a = (f32x4){0.f, 0.f, 0.f, 0.f};
    #pragma unroll
    for (int kc = 0; kc < SPLITK; ++kc) {
      const f32x4 v = p[(size_t)kc * ES4];
      a.x += v.x; a.y += v.y; a.z += v.z; a.w += v.w;
    }
    ((f32x4*)aggs)[gid] = a;
  } else {
    const int g2 = gid - ES4;
    const f32x4* p = (const f32x4*)Pv + g2;
    f32x4 a = (f32x4){0.f, 0.f, 0.f, 0.f};
    #pragma unroll
    for (int kc = 0; kc < SPLITK; ++kc) {
      const f32x4 v = p[(size_t)kc * EV4];
      a.x += v.x; a.y += v.y; a.z += v.z; a.w += v.w;
    }
    ((f32x4*)pvsum)[g2] = a;
  }
}

// ---------------------------------------------------------------------------
// node update (512 threads, 4-way K-split GEMVs).
// direct==1: av read directly from aggv ([v*3+d], layer-0 closed form).
// direct==0: av = C1 - x*C2 combined from pvsum ([d*64+v | 192+v]).
// ---------------------------------------------------------------------------
__global__ __launch_bounds__(512) void node_kernel(
    const float* __restrict__ aggs,     // [768][128]
    const float* __restrict__ pv_or_av, // [768][256] or [768][192]
    const float* __restrict__ x,
    const float* __restrict__ Wss,
    const float* __restrict__ Wvs,
    const float* __restrict__ Wvv,
    const float* __restrict__ Wsv_next,
    float* __restrict__ hs,
    float* __restrict__ hsv,
    float* __restrict__ hv,
    int has_next, int direct)
{
  __shared__ float as_l[FF];
  __shared__ float pvs_l[256];
  __shared__ float av_l[192];
  __shared__ float inv_l[VV];
  __shared__ float hsn[FF];
  __shared__ float red[512];
  __shared__ float red2[384];
  const int n = blockIdx.x, t = threadIdx.x;

  if (t < FF) as_l[t] = aggs[n * FF + t];
  if (direct) {
    if (t >= 128 && t < 320) av_l[t - 128] = pv_or_av[n * 192 + (t - 128)];
  } else {
    if (t >= 128 && t < 384) pvs_l[t - 128] = pv_or_av[n * 256 + (t - 128)];
  }
  __syncthreads();

  if (t < VV) {
    if (!direct) {
      const float base = pvs_l[192 + t];
      const float a0 = pvs_l[t]       - x[n * 3 + 0] * base;
      const float a1 = pvs_l[64 + t]  - x[n * 3 + 1] * base;
      const float a2 = pvs_l[128 + t] - x[n * 3 + 2] * base;
      av_l[t * 3 + 0] = a0; av_l[t * 3 + 1] = a1; av_l[t * 3 + 2] = a2;
      inv_l[t] = a0 * a0 + a1 * a1 + a2 * a2;
    } else {
      const float a0 = av_l[t * 3 + 0], a1 = av_l[t * 3 + 1], a2 = av_l[t * 3 + 2];
      inv_l[t] = a0 * a0 + a1 * a1 + a2 * a2;
    }
  }
  __syncthreads();

  // hs partials: 4-way split over K
  {
    const int f = t & 127, part = t >> 7;
    float acc = 0.f;
    const float* wp = Wss + (part * 32) * FF + f;
    #pragma unroll 8
    for (int kk = 0; kk < 32; ++kk) acc += as_l[part * 32 + kk] * wp[kk * FF];
    const float* vp = Wvs + (part * 16) * FF + f;
    #pragma unroll 8
    for (int vv = 0; vv < 16; ++vv) acc += inv_l[part * 16 + vv] * vp[vv * FF];
    red[part * 128 + f] = acc;
  }
  __syncthreads();

  // hs finalize || hv partials (2-way split over v)
  if (t < FF) {
    const float hnew =
        silu_f(hs[n * FF + t] + red[t] + red[128 + t] + red[256 + t] + red[384 + t]);
    hs[n * FF + t] = hnew;
    hsn[t] = hnew;
  }
  if (t < 384) {
    const int part = t / 192, j = t - part * 192;
    const int wv = j / 3, d = j - wv * 3;
    float acc = 0.f;
    const float* vp = Wvv + (part * 32) * VV + wv;
    #pragma unroll 8
    for (int v = 0; v < 32; ++v) acc += av_l[(part * 32 + v) * 3 + d] * vp[v * VV];
    red2[part * 192 + j] = acc;
  }
  __syncthreads();

  // hv finalize || hsv partials (4-way split over f)
  if (t < 192) hv[n * 192 + t] += red2[t] + red2[192 + t];
  if (has_next) {
    if (t < 256) {
      const int v = t & 63, part = t >> 6;
      float acc = 0.f;
      const float* wp = Wsv_next + (part * 32) * VV + v;
      #pragma unroll 8
      for (int f = 0; f < 32; ++f) acc += hsn[part * 32 + f] * wp[f * VV];
      red[t] = acc;
    }
    __syncthreads();
    if (t < VV) hsv[n * VV + t] = red[t] + red[64 + t] + red[128 + t] + red[192 + t];
  }
}

// ---------------------------------------------------------------------------
// readout (512 threads, K-split GEMVs)
// ---------------------------------------------------------------------------
__global__ __launch_bounds__(512) void readout_kernel(
    const float* __restrict__ hs,
    const float* __restrict__ hv,
    const float* __restrict__ Wro_s1,
    const float* __restrict__ Wro_s2,
    const float* __restrict__ Wro_v1,
    const float* __restrict__ Wro_v2,
    float* __restrict__ out)
{
  __shared__ float hs_l[FF];
  __shared__ float hv_l[192];
  __shared__ float t1[FF];
  __shared__ float tv1[192];
  __shared__ float redA[512];
  __shared__ float redB[384];
  const int n = blockIdx.x, t = threadIdx.x;
  if (t < FF) hs_l[t] = hs[n * FF + t];
  if (t >= 128 && t < 320) hv_l[t - 128] = hv[n * 192 + (t - 128)];
  __syncthreads();

  {
    const int f = t & 127, part = t >> 7;
    float acc = 0.f;
    const float* wp = Wro_s1 + (part * 32) * FF + f;
    #pragma unroll 8
    for (int kk = 0; kk < 32; ++kk) acc += hs_l[part * 32 + kk] * wp[kk * FF];
    redA[part * 128 + f] = acc;
  }
  __syncthreads();
  if (t < FF) t1[t] = silu_f(redA[t] + redA[128 + t] + redA[256 + t] + redA[384 + t]);
  if (t < 384) {
    const int part = t / 192, j = t - part * 192;
    const int wv = j / 3, d = j - wv * 3;
    float acc = 0.f;
    const float* vp = Wro_v1 + (part * 32) * VV + wv;
    #pragma unroll 8
    for (int v = 0; v < 32; ++v) acc += hv_l[(part * 32 + v) * 3 + d] * vp[v * VV];
    redB[part * 192 + j] = acc;
  }
  __syncthreads();
  if (t < 192) tv1[t] = redB[t] + redB[192 + t];
  if (t < 256) {
    const int o = t & 63, part = t >> 6;
    float acc = 0.f;
    const float* wp = Wro_s2 + (part * 32) * 64 + o;
    #pragma unroll 8
    for (int f = 0; f < 32; ++f) acc += t1[part * 32 + f] * wp[f * 64];
    redA[t] = acc;
  }
  __syncthreads();
  if (t < 64) out[n * 160 + t] = redA[t] + redA[64 + t] + redA[128 + t] + redA[192 + t];
  if (t < 192) {
    const int part = t / 96, j = t - part * 96;
    const int w2 = j / 3, d = j - w2 * 3;
    float acc = 0.f;
    const float* vp = Wro_v2 + (part * 32) * 32 + w2;
    #pragma unroll 8
    for (int wv = 0; wv < 32; ++wv) acc += tv1[(part * 32 + wv) * 3 + d] * vp[wv * 32];
    redB[part * 96 + j] = acc;
  }
  __syncthreads();
  if (t < 96) out[n * 160 + 64 + t] = redB[t] + redB[96 + t];
}

// ---------------------------------------------------------------------------
extern "C" void kernel_launch(void* const* d_in, const int* in_sizes, int n_in,
                              void* d_out, int out_size, void* d_ws, size_t ws_size,
                              hipStream_t stream) {
  const float* x      = (const float*)d_in[0];
  const float* embed  = (const float*)d_in[3];
  const float* Wr1    = (const float*)d_in[4];   // [2][1][16]
  const float* Wr2s   = (const float*)d_in[5];   // [2][16][128]
  const float* Wr2v   = (const float*)d_in[6];   // [2][16][64]
  const float* Wsv    = (const float*)d_in[7];   // [2][128][64]
  const float* Wss    = (const float*)d_in[8];   // [2][128][128]
  const float* Wvs    = (const float*)d_in[9];   // [2][64][128]
  const float* Wvv    = (const float*)d_in[10];  // [2][64][64]
  const float* Wro_s1 = (const float*)d_in[11];
  const float* Wro_s2 = (const float*)d_in[12];
  const float* Wro_v1 = (const float*)d_in[13];
  const float* Wro_v2 = (const float*)d_in[14];

  float* ws_f = (float*)d_ws;
  float* hs    = ws_f;                      // 768*128
  float* hsv   = hs + NN * FF;              // 768*64
  float* hv    = hsv + NN * VV;             // 768*192
  float* aggs  = hv + NN * 192;             // 768*128
  float* pvsum = aggs + NN * FF;            // 768*256 (L0: aggv 768*192)
  float* Ps    = pvsum + NN * 256;          // 24*768*128
  float* Pv    = Ps + (size_t)SPLITK * NN * FF;   // 24*768*256
  unsigned short* Bs = (unsigned short*)(Pv + (size_t)SPLITK * NN * 256);
  unsigned short* Bv = Bs + (size_t)12288 * 128;
  float* out = (float*)d_out;

  init_kernel<<<NN, 192, 0, stream>>>(embed, Wsv, hs, hsv, hv);

  // ---- layer 0: closed form (hs == embed everywhere) ----
  edge1_kernel<<<NN, 256, 0, stream>>>(x, hsv /* row0 = c[v] */, Wr1, Wr2s,
                                       Wr2v, embed, aggs, pvsum /*=aggv*/);
  node_kernel<<<NN, 512, 0, stream>>>(
      aggs, pvsum, x, Wss, Wvs, Wvv, Wsv + FF * VV, hs, hsv, hv,
      /*has_next=*/1, /*direct=*/1);

  // ---- layer 1: MFMA edge GEMM (R5 structure) ----
  prep_kernel<<<2304, 256, 0, stream>>>(
      hs, hsv, x, Wr2s + RH * FF, Wr2v + RH * VV, Bs, Bv);
  edge_gemm<<<MB_N * 2 * SPLITK, 256, 0, stream>>>(
      x, Bs, Bv, Wr1 + RH, Ps, Pv);
  reduce_kernel<<<(ES4 + EV4) / 256, 256, 0, stream>>>(Ps, Pv, aggs, pvsum);
  node_kernel<<<NN, 512, 0, stream>>>(
      aggs, pvsum, x, Wss + FF * FF, Wvs + VV * FF, Wvv + VV * VV, Wsv,
      hs, hsv, hv, /*has_next=*/0, /*direct=*/0);

  readout_kernel<<<NN, 512, 0, stream>>>(hs, hv, Wro_s1, Wro_s2, Wro_v1,
                                         Wro_v2, out);
}

// Round 11
// 70.370 us; speedup vs baseline: 2.7003x; 1.1183x over previous
//
#include <hip/hip_runtime.h>
#include <hip/hip_bf16.h>
#include <math.h>

#define NN 768
#define FF 128
#define VV 64
#define RH 16
#define SPLITK 24
#define SEND_PER_KC 32          // 768 / SPLITK
#define NITER 4                 // SEND_PER_KC / 8 senders per iter
#define KSTEPS 384              // 12288 / 32
#define NT_S 8                  // scalar n-tiles (128/16)
#define NT_V 16                 // vector n-tiles (256/16)
#define MB_N 24                 // M-blocks (768/32)
#define CHUNK 256
#define RPAD 260                // 256 + 4 pad: row stride % 32 = 4 -> 2-way max

typedef __attribute__((ext_vector_type(8))) short bf16x8_t;
typedef __attribute__((ext_vector_type(4))) float f32x4;

__device__ __forceinline__ float silu_f(float a) {
  return a * __builtin_amdgcn_rcpf(1.0f + __expf(-a));
}

__device__ __forceinline__ short f2bf(float f) {
  __hip_bfloat16 h = __float2bfloat16(f);  // RNE; pairs into v_cvt_pk_bf16_f32
  return __builtin_bit_cast(short, h);
}

// ---------------------------------------------------------------------------
// Layer-0 edge kernel (closed form, transposed LDS staging).
//   agg_s[r,f]   = embed[f]/64 * sum_h Wr2s[h,f] * R[r,h]
//   agg_v[r,v,d] = c[v]/64     * sum_h Wr2v[h,v] * T[r,h,d]
// with R[r,h] = sum_s rf, T[r,h,d] = sum_s rf*u_d ; c[v] = embed @ Wsv0
// (computed in-block -> init kernel eliminated).
// phase1: thread = sender, writes rf_t[h][s], u_t[{x,y,z,1}][s] (b32, no
// conflicts). phase2: thread = output j=(h,c), quarter q: float4 reads over
// 4 senders (b128; 2-way bank alias only, free).
// ---------------------------------------------------------------------------
__global__ __launch_bounds__(256) void edge1_kernel(
    const float* __restrict__ x,
    const float* __restrict__ Wr1,    // [16] layer-0 slice
    const float* __restrict__ Wr2s,   // [16][128]
    const float* __restrict__ Wr2v,   // [16][64]
    const float* __restrict__ embed,  // [128]
    const float* __restrict__ Wsv0,   // [128][64] layer-0 slice
    float* __restrict__ agg_s,        // [N][128]
    float* __restrict__ agg_v)        // [N][64*3]
{
  __shared__ float rf_t[RH * RPAD];   // [h][sender]
  __shared__ float u_t[4 * RPAD];     // [{ux,uy,uz,1}][sender]
  __shared__ float red[4][64];
  __shared__ float fin[64];
  __shared__ float cvs[64];

  const int r   = blockIdx.x;
  const int tid = threadIdx.x;
  const int j   = tid & 63;   // output index: h*4 + c
  const int q   = tid >> 6;   // sender quarter
  const int h   = j >> 2;
  const int c   = j & 3;
  const int sel = (c + 3) & 3;  // c==0 -> ones row (R); else u row c-1 (T)

  // c[v] = embed @ Wsv0 (once per block; replaces init kernel)
  if (tid < 64) {
    float a = 0.f;
    #pragma unroll 8
    for (int f = 0; f < FF; ++f) a += embed[f] * Wsv0[f * VV + tid];
    cvs[tid] = a;
  }

  float wr1[RH];
  #pragma unroll
  for (int hh = 0; hh < RH; ++hh) wr1[hh] = Wr1[hh];

  const float xr0 = x[r * 3 + 0], xr1 = x[r * 3 + 1], xr2 = x[r * 3 + 2];

  float acc = 0.f;
  for (int cb = 0; cb < NN; cb += CHUNK) {
    // ---- phase 1: thread = sender cb+tid (x is L1-resident, 9 KB) ----
    {
      const int s = cb + tid;
      const float vx = x[s * 3 + 0] - xr0;
      const float vy = x[s * 3 + 1] - xr1;
      const float vz = x[s * 3 + 2] - xr2;
      const float d  = __builtin_amdgcn_sqrtf(vx * vx + vy * vy + vz * vz);
      const float iv = __builtin_amdgcn_rcpf(d + 1e-8f);
      u_t[0 * RPAD + tid] = vx * iv;
      u_t[1 * RPAD + tid] = vy * iv;
      u_t[2 * RPAD + tid] = vz * iv;
      u_t[3 * RPAD + tid] = 1.0f;
      #pragma unroll
      for (int hh = 0; hh < RH; ++hh)
        rf_t[hh * RPAD + tid] = silu_f(d * wr1[hh]);
    }
    __syncthreads();

    // ---- phase 2: float4 over 4 senders per step ----
    const float* rp = &rf_t[h * RPAD + q * 64];
    const float* up = &u_t[sel * RPAD + q * 64];
    #pragma unroll 8
    for (int si = 0; si < 64; si += 4) {
      const float4 ra = *(const float4*)&rp[si];
      const float4 ua = *(const float4*)&up[si];
      acc += ra.x * ua.x + ra.y * ua.y + ra.z * ua.z + ra.w * ua.w;
    }
    __syncthreads();
  }

  red[q][j] = acc;
  __syncthreads();
  if (tid < 64) fin[tid] = red[0][tid] + red[1][tid] + red[2][tid] + red[3][tid];
  __syncthreads();

  if (tid < FF) {
    float a = 0.f;
    #pragma unroll
    for (int hh = 0; hh < RH; ++hh) a += fin[hh * 4] * Wr2s[hh * FF + tid];
    agg_s[(size_t)r * FF + tid] = a * embed[tid] * (1.0f / 64.0f);
  }
  if (tid < 192) {
    const int v = tid / 3, d = tid - v * 3;
    float a = 0.f;
    #pragma unroll
    for (int hh = 0; hh < RH; ++hh) a += fin[hh * 4 + 1 + d] * Wr2v[hh * VV + v];
    agg_v[(size_t)r * 192 + tid] = a * cvs[v] * (1.0f / 64.0f);
  }
}

// ---------------------------------------------------------------------------
// prep: build B matrices in MFMA-fragment-major layout (bf16). (verified)
// ---------------------------------------------------------------------------
__global__ __launch_bounds__(256) void prep_kernel(
    const float* __restrict__ hs, const float* __restrict__ hsv,
    const float* __restrict__ x,
    const float* __restrict__ Wr2s,   // [16][128] layer slice
    const float* __restrict__ Wr2v,   // [16][64]  layer slice
    unsigned short* __restrict__ Bs, unsigned short* __restrict__ Bv)
{
  const int gid   = blockIdx.x * 256 + threadIdx.x;
  const int lane  = gid & 63;
  const int tmp   = gid >> 6;
  const int ntile = tmp % 24;
  const int kstep = tmp / 24;
  if (kstep >= KSTEPS) return;
  const int qq = lane >> 4;              // octet index 0..3
  const int s  = kstep * 2 + (qq >> 1);
  const int hb = (qq & 1) * 8;

  bf16x8_t o;
  if (ntile < NT_S) {
    const int f = ntile * 16 + (lane & 15);
    const float hf = hs[s * FF + f] * 0.015625f;
    #pragma unroll
    for (int e = 0; e < 8; ++e)
      o[e] = f2bf(hf * Wr2s[(hb + e) * FF + f]);
    *(bf16x8_t*)&Bs[((size_t)(kstep * NT_S + ntile) * 64 + lane) * 8] = o;
  } else {
    const int nt2 = ntile - NT_S;
    const int n   = nt2 * 16 + (lane & 15);
    int v; float scale;
    if (n < 192) { const int dd = n >> 6; v = n & 63;
                   scale = x[s * 3 + dd] * hsv[s * VV + v] * 0.015625f; }
    else         { v = n - 192; scale = hsv[s * VV + v] * 0.015625f; }
    #pragma unroll
    for (int e = 0; e < 8; ++e)
      o[e] = f2bf(scale * Wr2v[(hb + e) * VV + v]);
    *(bf16x8_t*)&Bv[((size_t)(kstep * NT_V + nt2) * 64 + lane) * 8] = o;
  }
}

// ---------------------------------------------------------------------------
// edge GEMM (R10 verbatim): M=32/block, 4 waves, grid 1152, XCD-swizzled.
// ---------------------------------------------------------------------------
__global__ __launch_bounds__(256) void edge_gemm(
    const float* __restrict__ x,
    const unsigned short* __restrict__ Bs,
    const unsigned short* __restrict__ Bv,
    const float* __restrict__ Wr1,    // [16] layer slice
    float* __restrict__ Ps,           // [SPLITK][768][128]
    float* __restrict__ Pv)           // [SPLITK][768][256]
{
  __shared__ unsigned short A_lds[4 * 2 * 64 * 8];  // 8 KB

  const int wg  = ((blockIdx.x & 7) * 144) + (blockIdx.x >> 3);
  const int nt  = wg / 576;
  const int rem = wg - nt * 576;
  const int kc  = rem / MB_N;
  const int mb  = rem - kc * MB_N;

  const int tid  = threadIdx.x;
  const int lane = tid & 63;
  const int w    = tid >> 6;

  float wr1[RH];
  #pragma unroll
  for (int h = 0; h < RH; ++h) wr1[h] = Wr1[h];

  const int r_local = tid & 31;
  const int s_ii    = tid >> 5;        // 0..7
  const int r = mb * 32 + r_local;
  const int mt_w  = r_local >> 4;
  const int ks_w  = s_ii >> 1;
  const int lane0 = (r_local & 15) + ((s_ii & 1) << 5);

  const float xr0 = x[r * 3 + 0], xr1 = x[r * 3 + 1], xr2 = x[r * 3 + 2];
  float sx[NITER], sy[NITER], sz[NITER];
  #pragma unroll
  for (int it = 0; it < NITER; ++it) {
    const int s = kc * SEND_PER_KC + it * 8 + s_ii;
    sx[it] = x[s * 3 + 0]; sy[it] = x[s * 3 + 1]; sz[it] = x[s * 3 + 2];
  }

  f32x4 acc[8];
  #pragma unroll
  for (int i = 0; i < 8; ++i) acc[i] = (f32x4){0.f, 0.f, 0.f, 0.f};

  for (int it = 0; it < NITER; ++it) {
    {
      const float vx = sx[it] - xr0;
      const float vy = sy[it] - xr1;
      const float vz = sz[it] - xr2;
      const float dd = __builtin_amdgcn_sqrtf(vx * vx + vy * vy + vz * vz);
      const float mulf = nt ? __builtin_amdgcn_rcpf(dd + 1e-8f) : 1.0f;
      bf16x8_t o0, o1;
      #pragma unroll
      for (int h = 0; h < 8; ++h)
        o0[h] = f2bf(silu_f(dd * wr1[h]) * mulf);
      #pragma unroll
      for (int h = 8; h < 16; ++h)
        o1[h - 8] = f2bf(silu_f(dd * wr1[h]) * mulf);
      *(bf16x8_t*)&A_lds[((ks_w * 2 + mt_w) * 64 + lane0) * 8]      = o0;
      *(bf16x8_t*)&A_lds[((ks_w * 2 + mt_w) * 64 + lane0 + 16) * 8] = o1;
    }
    __syncthreads();

    const int kgb = kc * (SEND_PER_KC / 2) + it * 4;
    if (nt == 0) {
      #pragma unroll
      for (int ks = 0; ks < 4; ++ks) {
        const bf16x8_t b0 =
            *(const bf16x8_t*)&Bs[((size_t)((kgb + ks) * NT_S + 2 * w) * 64 + lane) * 8];
        const bf16x8_t b1 =
            *(const bf16x8_t*)&Bs[((size_t)((kgb + ks) * NT_S + 2 * w + 1) * 64 + lane) * 8];
        #pragma unroll
        for (int mt = 0; mt < 2; ++mt) {
          const bf16x8_t a =
              *(const bf16x8_t*)&A_lds[((ks * 2 + mt) * 64 + lane) * 8];
          acc[mt * 2 + 0] = __builtin_amdgcn_mfma_f32_16x16x32_bf16(a, b0, acc[mt * 2 + 0], 0, 0, 0);
          acc[mt * 2 + 1] = __builtin_amdgcn_mfma_f32_16x16x32_bf16(a, b1, acc[mt * 2 + 1], 0, 0, 0);
        }
      }
    } else {
      #pragma unroll
      for (int ks = 0; ks < 4; ++ks) {
        bf16x8_t bv[4];
        #pragma unroll
        for (int j = 0; j < 4; ++j)
          bv[j] = *(const bf16x8_t*)&Bv[((size_t)((kgb + ks) * NT_V + 4 * w + j) * 64 + lane) * 8];
        #pragma unroll
        for (int mt = 0; mt < 2; ++mt) {
          const bf16x8_t a =
              *(const bf16x8_t*)&A_lds[((ks * 2 + mt) * 64 + lane) * 8];
          #pragma unroll
          for (int j = 0; j < 4; ++j)
            acc[mt * 4 + j] = __builtin_amdgcn_mfma_f32_16x16x32_bf16(a, bv[j], acc[mt * 4 + j], 0, 0, 0);
        }
      }
    }
    __syncthreads();
  }

  const int rowq = (lane >> 4) << 2;
  if (nt == 0) {
    #pragma unroll
    for (int j = 0; j < 2; ++j) {
      const int col = (2 * w + j) * 16 + (lane & 15);
      #pragma unroll
      for (int mt = 0; mt < 2; ++mt) {
        #pragma unroll
        for (int reg = 0; reg < 4; ++reg) {
          const int row = mb * 32 + mt * 16 + rowq + reg;
          Ps[((size_t)kc * NN + row) * FF + col] = acc[mt * 2 + j][reg];
        }
      }
    }
  } else {
    #pragma unroll
    for (int j = 0; j < 4; ++j) {
      const int col = (4 * w + j) * 16 + (lane & 15);
      #pragma unroll
      for (int mt = 0; mt < 2; ++mt) {
        #pragma unroll
        for (int reg = 0; reg < 4; ++reg) {
          const int row = mb * 32 + mt * 16 + rowq + reg;
          Pv[((size_t)kc * NN + row) * 256 + col] = acc[mt * 4 + j][reg];
        }
      }
    }
  }
}

// ---------------------------------------------------------------------------
// node update (512 threads) with FUSED splitK reduction + init mode.
// direct==1 (layer 0): Ps/Pv are aggs[768][128] / aggv[768][192];
//   hs_prev = embed, hv_prev = 0 (init kernel eliminated).
// direct==0 (layer 1): Ps/Pv are [SPLITK] partial planes, reduced inline;
//   av = C1 - x*C2 from pvsum layout [d*64+v | 192+v].
// ---------------------------------------------------------------------------
__global__ __launch_bounds__(512) void node_kernel(
    const float* __restrict__ Ps,
    const float* __restrict__ Pv,
    const float* __restrict__ x,
    const float* __restrict__ embed,
    const float* __restrict__ Wss,
    const float* __restrict__ Wvs,
    const float* __restrict__ Wvv,
    const float* __restrict__ Wsv_next,
    float* __restrict__ hs,
    float* __restrict__ hsv,
    float* __restrict__ hv,
    int has_next, int direct)
{
  __shared__ float as_l[FF];
  __shared__ float pvs_l[256];
  __shared__ float av_l[192];
  __shared__ float inv_l[VV];
  __shared__ float hsn[FF];
  __shared__ float red[512];
  __shared__ float red2[384];
  const int n = blockIdx.x, t = threadIdx.x;

  if (direct) {
    if (t < FF) as_l[t] = Ps[n * FF + t];
    if (t >= 128 && t < 320) av_l[t - 128] = Pv[n * 192 + (t - 128)];
  } else {
    if (t < FF) {
      float a = 0.f;
      #pragma unroll
      for (int kc = 0; kc < SPLITK; ++kc) a += Ps[((size_t)kc * NN + n) * FF + t];
      as_l[t] = a;
    } else if (t < 384) {
      const int cc = t - 128;
      float a = 0.f;
      #pragma unroll
      for (int kc = 0; kc < SPLITK; ++kc) a += Pv[((size_t)kc * NN + n) * 256 + cc];
      pvs_l[cc] = a;
    }
  }
  __syncthreads();

  if (t < VV) {
    float a0, a1, a2;
    if (direct) {
      a0 = av_l[t * 3 + 0]; a1 = av_l[t * 3 + 1]; a2 = av_l[t * 3 + 2];
    } else {
      const float base = pvs_l[192 + t];
      a0 = pvs_l[t]       - x[n * 3 + 0] * base;
      a1 = pvs_l[64 + t]  - x[n * 3 + 1] * base;
      a2 = pvs_l[128 + t] - x[n * 3 + 2] * base;
      av_l[t * 3 + 0] = a0; av_l[t * 3 + 1] = a1; av_l[t * 3 + 2] = a2;
    }
    inv_l[t] = a0 * a0 + a1 * a1 + a2 * a2;
  }
  __syncthreads();

  // hs partials: 4-way split over K
  {
    const int f = t & 127, part = t >> 7;
    float acc = 0.f;
    const float* wp = Wss + (part * 32) * FF + f;
    #pragma unroll 8
    for (int kk = 0; kk < 32; ++kk) acc += as_l[part * 32 + kk] * wp[kk * FF];
    const float* vp = Wvs + (part * 16) * FF + f;
    #pragma unroll 8
    for (int vv = 0; vv < 16; ++vv) acc += inv_l[part * 16 + vv] * vp[vv * FF];
    red[part * 128 + f] = acc;
  }
  __syncthreads();

  // hs finalize || hv partials (2-way split over v)
  if (t < FF) {
    const float hprev = direct ? embed[t] : hs[n * FF + t];
    const float hnew =
        silu_f(hprev + red[t] + red[128 + t] + red[256 + t] + red[384 + t]);
    hs[n * FF + t] = hnew;
    hsn[t] = hnew;
  }
  if (t < 384) {
    const int part = t / 192, j = t - part * 192;
    const int wv = j / 3, d = j - wv * 3;
    float acc = 0.f;
    const float* vp = Wvv + (part * 32) * VV + wv;
    #pragma unroll 8
    for (int v = 0; v < 32; ++v) acc += av_l[(part * 32 + v) * 3 + d] * vp[v * VV];
    red2[part * 192 + j] = acc;
  }
  __syncthreads();

  // hv finalize || hsv partials (4-way split over f)
  if (t < 192) {
    const float hvprev = direct ? 0.f : hv[n * 192 + t];
    hv[n * 192 + t] = hvprev + red2[t] + red2[192 + t];
  }
  if (has_next) {
    if (t < 256) {
      const int v = t & 63, part = t >> 6;
      float acc = 0.f;
      const float* wp = Wsv_next + (part * 32) * VV + v;
      #pragma unroll 8
      for (int f = 0; f < 32; ++f) acc += hsn[part * 32 + f] * wp[f * VV];
      red[t] = acc;
    }
    __syncthreads();
    if (t < VV) hsv[n * VV + t] = red[t] + red[64 + t] + red[128 + t] + red[192 + t];
  }
}

// ---------------------------------------------------------------------------
// readout (512 threads, K-split GEMVs)
// ---------------------------------------------------------------------------
__global__ __launch_bounds__(512) void readout_kernel(
    const float* __restrict__ hs,
    const float* __restrict__ hv,
    const float* __restrict__ Wro_s1,
    const float* __restrict__ Wro_s2,
    const float* __restrict__ Wro_v1,
    const float* __restrict__ Wro_v2,
    float* __restrict__ out)
{
  __shared__ float hs_l[FF];
  __shared__ float hv_l[192];
  __shared__ float t1[FF];
  __shared__ float tv1[192];
  __shared__ float redA[512];
  __shared__ float redB[384];
  const int n = blockIdx.x, t = threadIdx.x;
  if (t < FF) hs_l[t] = hs[n * FF + t];
  if (t >= 128 && t < 320) hv_l[t - 128] = hv[n * 192 + (t - 128)];
  __syncthreads();

  {
    const int f = t & 127, part = t >> 7;
    float acc = 0.f;
    const float* wp = Wro_s1 + (part * 32) * FF + f;
    #pragma unroll 8
    for (int kk = 0; kk < 32; ++kk) acc += hs_l[part * 32 + kk] * wp[kk * FF];
    redA[part * 128 + f] = acc;
  }
  __syncthreads();
  if (t < FF) t1[t] = silu_f(redA[t] + redA[128 + t] + redA[256 + t] + redA[384 + t]);
  if (t < 384) {
    const int part = t / 192, j = t - part * 192;
    const int wv = j / 3, d = j - wv * 3;
    float acc = 0.f;
    const float* vp = Wro_v1 + (part * 32) * VV + wv;
    #pragma unroll 8
    for (int v = 0; v < 32; ++v) acc += hv_l[(part * 32 + v) * 3 + d] * vp[v * VV];
    redB[part * 192 + j] = acc;
  }
  __syncthreads();
  if (t < 192) tv1[t] = redB[t] + redB[192 + t];
  if (t < 256) {
    const int o = t & 63, part = t >> 6;
    float acc = 0.f;
    const float* wp = Wro_s2 + (part * 32) * 64 + o;
    #pragma unroll 8
    for (int f = 0; f < 32; ++f) acc += t1[part * 32 + f] * wp[f * 64];
    redA[t] = acc;
  }
  __syncthreads();
  if (t < 64) out[n * 160 + t] = redA[t] + redA[64 + t] + redA[128 + t] + redA[192 + t];
  if (t < 192) {
    const int part = t / 96, j = t - part * 96;
    const int w2 = j / 3, d = j - w2 * 3;
    float acc = 0.f;
    const float* vp = Wro_v2 + (part * 32) * 32 + w2;
    #pragma unroll 8
    for (int wv = 0; wv < 32; ++wv) acc += tv1[(part * 32 + wv) * 3 + d] * vp[wv * 32];
    redB[part * 96 + j] = acc;
  }
  __syncthreads();
  if (t < 96) out[n * 160 + 64 + t] = redB[t] + redB[96 + t];
}

// ---------------------------------------------------------------------------
extern "C" void kernel_launch(void* const* d_in, const int* in_sizes, int n_in,
                              void* d_out, int out_size, void* d_ws, size_t ws_size,
                              hipStream_t stream) {
  const float* x      = (const float*)d_in[0];
  const float* embed  = (const float*)d_in[3];
  const float* Wr1    = (const float*)d_in[4];   // [2][1][16]
  const float* Wr2s   = (const float*)d_in[5];   // [2][16][128]
  const float* Wr2v   = (const float*)d_in[6];   // [2][16][64]
  const float* Wsv    = (const float*)d_in[7];   // [2][128][64]
  const float* Wss    = (const float*)d_in[8];   // [2][128][128]
  const float* Wvs    = (const float*)d_in[9];   // [2][64][128]
  const float* Wvv    = (const float*)d_in[10];  // [2][64][64]
  const float* Wro_s1 = (const float*)d_in[11];
  const float* Wro_s2 = (const float*)d_in[12];
  const float* Wro_v1 = (const float*)d_in[13];
  const float* Wro_v2 = (const float*)d_in[14];

  float* ws_f = (float*)d_ws;
  float* hs    = ws_f;                      // 768*128
  float* hsv   = hs + NN * FF;              // 768*64
  float* hv    = hsv + NN * VV;             // 768*192
  float* aggs  = hv + NN * 192;             // 768*128
  float* aggv  = aggs + NN * FF;            // 768*192 (layer-0 direct av)
  float* Ps    = aggv + NN * 256;           // 24*768*128
  float* Pv    = Ps + (size_t)SPLITK * NN * FF;   // 24*768*256
  unsigned short* Bs = (unsigned short*)(Pv + (size_t)SPLITK * NN * 256);
  unsigned short* Bv = Bs + (size_t)12288 * 128;
  float* out = (float*)d_out;

  // ---- layer 0: closed form (hs == embed everywhere), init folded in ----
  edge1_kernel<<<NN, 256, 0, stream>>>(x, Wr1, Wr2s, Wr2v, embed, Wsv,
                                       aggs, aggv);
  node_kernel<<<NN, 512, 0, stream>>>(
      aggs, aggv, x, embed, Wss, Wvs, Wvv, Wsv + FF * VV, hs, hsv, hv,
      /*has_next=*/1, /*direct=*/1);

  // ---- layer 1: MFMA edge GEMM (R10 structure), reduce fused into node ----
  prep_kernel<<<2304, 256, 0, stream>>>(
      hs, hsv, x, Wr2s + RH * FF, Wr2v + RH * VV, Bs, Bv);
  edge_gemm<<<MB_N * 2 * SPLITK, 256, 0, stream>>>(
      x, Bs, Bv, Wr1 + RH, Ps, Pv);
  node_kernel<<<NN, 512, 0, stream>>>(
      Ps, Pv, x, embed, Wss + FF * FF, Wvs + VV * FF, Wvv + VV * VV, Wsv,
      hs, hsv, hv, /*has_next=*/0, /*direct=*/0);

  readout_kernel<<<NN, 512, 0, stream>>>(hs, hv, Wro_s1, Wro_s2, Wro_v1,
                                         Wro_v2, out);
}

// Round 12
// 65.097 us; speedup vs baseline: 2.9190x; 1.0810x over previous
//
#include <hip/hip_runtime.h>
#include <hip/hip_bf16.h>
#include <math.h>

#define NN 768
#define FF 128
#define VV 64
#define RH 16
#define SPLITK 24
#define SEND_PER_KC 32          // 768 / SPLITK
#define NITER 4                 // SEND_PER_KC / 8 senders per iter
#define KSTEPS 384              // 12288 / 32
#define NT_S 8                  // scalar n-tiles (128/16)
#define NT_V 16                 // vector n-tiles (256/16)
#define MB_N 24                 // M-blocks (768/32)
#define CHUNK 256
#define RPAD 260                // 256 + 4 pad: row stride % 32 = 4 -> 2-way max

typedef __attribute__((ext_vector_type(8))) short bf16x8_t;
typedef __attribute__((ext_vector_type(4))) float f32x4;

__device__ __forceinline__ float silu_f(float a) {
  return a * __builtin_amdgcn_rcpf(1.0f + __expf(-a));
}

__device__ __forceinline__ short f2bf(float f) {
  __hip_bfloat16 h = __float2bfloat16(f);  // RNE; pairs into v_cvt_pk_bf16_f32
  return __builtin_bit_cast(short, h);
}

// ---------------------------------------------------------------------------
// Layer-0 fused kernel: closed-form edge pass (verified R11) + node update
// (init folded). One block per receiver r, 256 threads.
//   R[r,h] = sum_s rf ; T[r,h,d] = sum_s rf*u_d ; c[v] = embed @ Wsv0
//   as[f] = embed[f]/64 * sum_h Wr2s[h,f]*R ; av[v,d] = c[v]/64 * sum_h Wr2v*T
//   hs = silu(embed + as@Wss + |av|^2@Wvs); hv = av@Wvv; hsv = hs@Wsv1
// ---------------------------------------------------------------------------
__global__ __launch_bounds__(256) void layer0_kernel(
    const float* __restrict__ x,
    const float* __restrict__ Wr1,    // [16] layer-0
    const float* __restrict__ Wr2s,   // [16][128] layer-0
    const float* __restrict__ Wr2v,   // [16][64]  layer-0
    const float* __restrict__ embed,  // [128]
    const float* __restrict__ Wsv0,   // [128][64] layer-0
    const float* __restrict__ Wss,    // [128][128] layer-0
    const float* __restrict__ Wvs,    // [64][128]  layer-0
    const float* __restrict__ Wvv,    // [64][64]   layer-0
    const float* __restrict__ Wsv1,   // [128][64]  layer-1 (for hsv)
    float* __restrict__ hs,
    float* __restrict__ hsv,
    float* __restrict__ hv)
{
  __shared__ float rf_t[RH * RPAD];   // [h][sender]
  __shared__ float u_t[4 * RPAD];     // [{ux,uy,uz,1}][sender]
  __shared__ float red[4][64];
  __shared__ float fin[64];
  __shared__ float cvs[64];
  __shared__ float as_l[FF];
  __shared__ float av_l[192];
  __shared__ float inv_l[VV];
  __shared__ float hsn[FF];
  __shared__ float redn[256];

  const int r   = blockIdx.x;
  const int tid = threadIdx.x;
  const int j   = tid & 63;   // output index: h*4 + c
  const int q   = tid >> 6;   // sender quarter
  const int h   = j >> 2;
  const int c   = j & 3;
  const int sel = (c + 3) & 3;  // c==0 -> ones row (R); else u row c-1 (T)

  // c[v] = embed @ Wsv0
  if (tid < 64) {
    float a = 0.f;
    #pragma unroll 8
    for (int f = 0; f < FF; ++f) a += embed[f] * Wsv0[f * VV + tid];
    cvs[tid] = a;
  }

  float wr1[RH];
  #pragma unroll
  for (int hh = 0; hh < RH; ++hh) wr1[hh] = Wr1[hh];

  const float xr0 = x[r * 3 + 0], xr1 = x[r * 3 + 1], xr2 = x[r * 3 + 2];

  float acc = 0.f;
  for (int cb = 0; cb < NN; cb += CHUNK) {
    // phase 1: thread = sender cb+tid (x is L1-resident, 9 KB)
    {
      const int s = cb + tid;
      const float vx = x[s * 3 + 0] - xr0;
      const float vy = x[s * 3 + 1] - xr1;
      const float vz = x[s * 3 + 2] - xr2;
      const float d  = __builtin_amdgcn_sqrtf(vx * vx + vy * vy + vz * vz);
      const float iv = __builtin_amdgcn_rcpf(d + 1e-8f);
      u_t[0 * RPAD + tid] = vx * iv;
      u_t[1 * RPAD + tid] = vy * iv;
      u_t[2 * RPAD + tid] = vz * iv;
      u_t[3 * RPAD + tid] = 1.0f;
      #pragma unroll
      for (int hh = 0; hh < RH; ++hh)
        rf_t[hh * RPAD + tid] = silu_f(d * wr1[hh]);
    }
    __syncthreads();

    // phase 2: float4 over 4 senders per step
    const float* rp = &rf_t[h * RPAD + q * 64];
    const float* up = &u_t[sel * RPAD + q * 64];
    #pragma unroll 8
    for (int si = 0; si < 64; si += 4) {
      const float4 ra = *(const float4*)&rp[si];
      const float4 ua = *(const float4*)&up[si];
      acc += ra.x * ua.x + ra.y * ua.y + ra.z * ua.z + ra.w * ua.w;
    }
    __syncthreads();
  }

  red[q][j] = acc;
  __syncthreads();
  if (tid < 64) fin[tid] = red[0][tid] + red[1][tid] + red[2][tid] + red[3][tid];
  __syncthreads();

  // agg into LDS (no global round trip)
  if (tid < FF) {
    float a = 0.f;
    #pragma unroll
    for (int hh = 0; hh < RH; ++hh) a += fin[hh * 4] * Wr2s[hh * FF + tid];
    as_l[tid] = a * embed[tid] * (1.0f / 64.0f);
  }
  if (tid < 192) {
    const int v = tid / 3, d = tid - v * 3;
    float a = 0.f;
    #pragma unroll
    for (int hh = 0; hh < RH; ++hh) a += fin[hh * 4 + 1 + d] * Wr2v[hh * VV + v];
    av_l[tid] = a * cvs[v] * (1.0f / 64.0f);
  }
  __syncthreads();

  if (tid < VV) {
    const float a0 = av_l[tid * 3 + 0], a1 = av_l[tid * 3 + 1], a2 = av_l[tid * 3 + 2];
    inv_l[tid] = a0 * a0 + a1 * a1 + a2 * a2;
  }
  __syncthreads();

  // hs partials: 2-way K split over 256 threads
  {
    const int f = tid & 127, part = tid >> 7;   // 0/1
    float a = 0.f;
    const float* wp = Wss + (part * 64) * FF + f;
    #pragma unroll 8
    for (int kk = 0; kk < 64; ++kk) a += as_l[part * 64 + kk] * wp[kk * FF];
    const float* vp = Wvs + (part * 32) * FF + f;
    #pragma unroll 8
    for (int vv = 0; vv < 32; ++vv) a += inv_l[part * 32 + vv] * vp[vv * FF];
    redn[part * 128 + f] = a;
  }
  __syncthreads();

  if (tid < FF) {
    const float hnew = silu_f(embed[tid] + redn[tid] + redn[128 + tid]);
    hs[(size_t)r * FF + tid] = hnew;
    hsn[tid] = hnew;
  }
  // hv = av @ Wvv (hv_prev = 0)
  if (tid < 192) {
    const int w = tid / 3, d = tid - w * 3;
    float a = 0.f;
    #pragma unroll 8
    for (int v = 0; v < VV; ++v) a += av_l[v * 3 + d] * Wvv[v * VV + w];
    hv[(size_t)r * 192 + tid] = a;
  }
  __syncthreads();

  // hsv = hsn @ Wsv1 : 4-way split
  {
    const int v = tid & 63, part = tid >> 6;   // 0..3
    float a = 0.f;
    const float* wp = Wsv1 + (part * 32) * VV + v;
    #pragma unroll 8
    for (int f = 0; f < 32; ++f) a += hsn[part * 32 + f] * wp[f * VV];
    redn[tid] = a;
  }
  __syncthreads();
  if (tid < VV)
    hsv[(size_t)r * VV + tid] = redn[tid] + redn[64 + tid] + redn[128 + tid] + redn[192 + tid];
}

// ---------------------------------------------------------------------------
// prep: build B matrices in MFMA-fragment-major layout (bf16). (verified)
// ---------------------------------------------------------------------------
__global__ __launch_bounds__(256) void prep_kernel(
    const float* __restrict__ hs, const float* __restrict__ hsv,
    const float* __restrict__ x,
    const float* __restrict__ Wr2s,   // [16][128] layer-1 slice
    const float* __restrict__ Wr2v,   // [16][64]  layer-1 slice
    unsigned short* __restrict__ Bs, unsigned short* __restrict__ Bv)
{
  const int gid   = blockIdx.x * 256 + threadIdx.x;
  const int lane  = gid & 63;
  const int tmp   = gid >> 6;
  const int ntile = tmp % 24;
  const int kstep = tmp / 24;
  if (kstep >= KSTEPS) return;
  const int qq = lane >> 4;              // octet index 0..3
  const int s  = kstep * 2 + (qq >> 1);
  const int hb = (qq & 1) * 8;

  bf16x8_t o;
  if (ntile < NT_S) {
    const int f = ntile * 16 + (lane & 15);
    const float hf = hs[s * FF + f] * 0.015625f;
    #pragma unroll
    for (int e = 0; e < 8; ++e)
      o[e] = f2bf(hf * Wr2s[(hb + e) * FF + f]);
    *(bf16x8_t*)&Bs[((size_t)(kstep * NT_S + ntile) * 64 + lane) * 8] = o;
  } else {
    const int nt2 = ntile - NT_S;
    const int n   = nt2 * 16 + (lane & 15);
    int v; float scale;
    if (n < 192) { const int dd = n >> 6; v = n & 63;
                   scale = x[s * 3 + dd] * hsv[s * VV + v] * 0.015625f; }
    else         { v = n - 192; scale = hsv[s * VV + v] * 0.015625f; }
    #pragma unroll
    for (int e = 0; e < 8; ++e)
      o[e] = f2bf(scale * Wr2v[(hb + e) * VV + v]);
    *(bf16x8_t*)&Bv[((size_t)(kstep * NT_V + nt2) * 64 + lane) * 8] = o;
  }
}

// ---------------------------------------------------------------------------
// edge GEMM v7 (combined kinds): M=32/block, 4 waves, grid = 24 mb x 24 kc
// = 576 blocks. Each block computes the silu chain ONCE per (r,s) pair and
// feeds BOTH the scalar path (A_lds) and vector path (G_lds = A * iv).
// Wave w: scalar ntiles 2w,2w+1 and vector ntiles 4w..4w+3, mtiles 0,1.
// Fragment indexing identical to the verified R5/R10 kernel. XCD swizzle:
// each XCD owns 3 whole kc slices (B slice 384 KB x3, L2-resident).
// ---------------------------------------------------------------------------
__global__ __launch_bounds__(256) void edge_gemm(
    const float* __restrict__ x,
    const unsigned short* __restrict__ Bs,
    const unsigned short* __restrict__ Bv,
    const float* __restrict__ Wr1,    // [16] layer-1 slice
    float* __restrict__ Ps,           // [SPLITK][768][128]
    float* __restrict__ Pv)           // [SPLITK][768][256]
{
  __shared__ unsigned short A_lds[4 * 2 * 64 * 8];  // 8 KB scalar A
  __shared__ unsigned short G_lds[4 * 2 * 64 * 8];  // 8 KB vector A (rf*iv)

  // bijective XCD swizzle: 576 = 8 * 72; xcd owns kc in [3*xcd, 3*xcd+2]
  const int wg = ((blockIdx.x & 7) * 72) + (blockIdx.x >> 3);
  const int kc = wg / MB_N;
  const int mb = wg - kc * MB_N;

  const int tid  = threadIdx.x;
  const int lane = tid & 63;
  const int w    = tid >> 6;

  float wr1[RH];
  #pragma unroll
  for (int h = 0; h < RH; ++h) wr1[h] = Wr1[h];

  const int r_local = tid & 31;
  const int s_ii    = tid >> 5;        // 0..7
  const int r = mb * 32 + r_local;
  const int mt_w  = r_local >> 4;
  const int ks_w  = s_ii >> 1;
  const int lane0 = (r_local & 15) + ((s_ii & 1) << 5);

  const float xr0 = x[r * 3 + 0], xr1 = x[r * 3 + 1], xr2 = x[r * 3 + 2];
  float sx[NITER], sy[NITER], sz[NITER];
  #pragma unroll
  for (int it = 0; it < NITER; ++it) {
    const int s = kc * SEND_PER_KC + it * 8 + s_ii;
    sx[it] = x[s * 3 + 0]; sy[it] = x[s * 3 + 1]; sz[it] = x[s * 3 + 2];
  }

  f32x4 accS[4], accV[8];
  #pragma unroll
  for (int i = 0; i < 4; ++i) accS[i] = (f32x4){0.f, 0.f, 0.f, 0.f};
  #pragma unroll
  for (int i = 0; i < 8; ++i) accV[i] = (f32x4){0.f, 0.f, 0.f, 0.f};

  for (int it = 0; it < NITER; ++it) {
    // ---- A generation: silu chain ONCE, two LDS images ----
    {
      const float vx = sx[it] - xr0;
      const float vy = sy[it] - xr1;
      const float vz = sz[it] - xr2;
      const float dd = __builtin_amdgcn_sqrtf(vx * vx + vy * vy + vz * vz);
      const float iv = __builtin_amdgcn_rcpf(dd + 1e-8f);
      float sv[RH];
      #pragma unroll
      for (int h = 0; h < RH; ++h) sv[h] = silu_f(dd * wr1[h]);
      bf16x8_t o0, o1, g0, g1;
      #pragma unroll
      for (int h = 0; h < 8; ++h) {
        o0[h] = f2bf(sv[h]);
        o1[h] = f2bf(sv[h + 8]);
        g0[h] = f2bf(sv[h] * iv);
        g1[h] = f2bf(sv[h + 8] * iv);
      }
      const int off0 = ((ks_w * 2 + mt_w) * 64 + lane0) * 8;
      *(bf16x8_t*)&A_lds[off0]       = o0;
      *(bf16x8_t*)&A_lds[off0 + 128] = o1;   // +16 lanes * 8
      *(bf16x8_t*)&G_lds[off0]       = g0;
      *(bf16x8_t*)&G_lds[off0 + 128] = g1;
    }
    __syncthreads();

    // ---- MFMA: scalar (2 nt) + vector (4 nt) per wave ----
    const int kgb = kc * (SEND_PER_KC / 2) + it * 4;
    #pragma unroll
    for (int ks = 0; ks < 4; ++ks) {
      const bf16x8_t b0 =
          *(const bf16x8_t*)&Bs[((size_t)((kgb + ks) * NT_S + 2 * w) * 64 + lane) * 8];
      const bf16x8_t b1 =
          *(const bf16x8_t*)&Bs[((size_t)((kgb + ks) * NT_S + 2 * w + 1) * 64 + lane) * 8];
      bf16x8_t bv[4];
      #pragma unroll
      for (int j = 0; j < 4; ++j)
        bv[j] = *(const bf16x8_t*)&Bv[((size_t)((kgb + ks) * NT_V + 4 * w + j) * 64 + lane) * 8];
      #pragma unroll
      for (int mt = 0; mt < 2; ++mt) {
        const int aoff = ((ks * 2 + mt) * 64 + lane) * 8;
        const bf16x8_t a  = *(const bf16x8_t*)&A_lds[aoff];
        const bf16x8_t ag = *(const bf16x8_t*)&G_lds[aoff];
        accS[mt * 2 + 0] = __builtin_amdgcn_mfma_f32_16x16x32_bf16(a, b0, accS[mt * 2 + 0], 0, 0, 0);
        accS[mt * 2 + 1] = __builtin_amdgcn_mfma_f32_16x16x32_bf16(a, b1, accS[mt * 2 + 1], 0, 0, 0);
        #pragma unroll
        for (int j = 0; j < 4; ++j)
          accV[mt * 4 + j] = __builtin_amdgcn_mfma_f32_16x16x32_bf16(ag, bv[j], accV[mt * 4 + j], 0, 0, 0);
      }
    }
    __syncthreads();
  }

  // ---- epilogue: write partials (verified R5 pattern, both kinds) ----
  const int rowq = (lane >> 4) << 2;
  #pragma unroll
  for (int j = 0; j < 2; ++j) {
    const int col = (2 * w + j) * 16 + (lane & 15);
    #pragma unroll
    for (int mt = 0; mt < 2; ++mt) {
      #pragma unroll
      for (int reg = 0; reg < 4; ++reg) {
        const int row = mb * 32 + mt * 16 + rowq + reg;
        Ps[((size_t)kc * NN + row) * FF + col] = accS[mt * 2 + j][reg];
      }
    }
  }
  #pragma unroll
  for (int j = 0; j < 4; ++j) {
    const int col = (4 * w + j) * 16 + (lane & 15);
    #pragma unroll
    for (int mt = 0; mt < 2; ++mt) {
      #pragma unroll
      for (int reg = 0; reg < 4; ++reg) {
        const int row = mb * 32 + mt * 16 + rowq + reg;
        Pv[((size_t)kc * NN + row) * 256 + col] = accV[mt * 4 + j][reg];
      }
    }
  }
}

// ---------------------------------------------------------------------------
// final kernel: node1 (fused splitK reduce, verified R11) + readout, fused.
// hs/hv of layer 1 live only in LDS (never written to global).
// ---------------------------------------------------------------------------
__global__ __launch_bounds__(512) void final_kernel(
    const float* __restrict__ Ps,       // [SPLITK][768][128]
    const float* __restrict__ Pv,       // [SPLITK][768][256]
    const float* __restrict__ x,
    const float* __restrict__ hs,       // layer-0 output
    const float* __restrict__ hv,       // layer-0 output
    const float* __restrict__ Wss,      // layer-1
    const float* __restrict__ Wvs,      // layer-1
    const float* __restrict__ Wvv,      // layer-1
    const float* __restrict__ Wro_s1,
    const float* __restrict__ Wro_s2,
    const float* __restrict__ Wro_v1,
    const float* __restrict__ Wro_v2,
    float* __restrict__ out)
{
  __shared__ float as_l[FF];
  __shared__ float pvs_l[256];
  __shared__ float av_l[192];
  __shared__ float inv_l[VV];
  __shared__ float hsn[FF];
  __shared__ float hv_l[192];
  __shared__ float red[512];
  __shared__ float red2[384];
  __shared__ float t1[FF];
  __shared__ float tv1[192];
  const int n = blockIdx.x, t = threadIdx.x;

  // fused splitK reduce
  if (t < FF) {
    float a = 0.f;
    #pragma unroll
    for (int kc = 0; kc < SPLITK; ++kc) a += Ps[((size_t)kc * NN + n) * FF + t];
    as_l[t] = a;
  } else if (t < 384) {
    const int cc = t - 128;
    float a = 0.f;
    #pragma unroll
    for (int kc = 0; kc < SPLITK; ++kc) a += Pv[((size_t)kc * NN + n) * 256 + cc];
    pvs_l[cc] = a;
  }
  __syncthreads();

  if (t < VV) {
    const float base = pvs_l[192 + t];
    const float a0 = pvs_l[t]       - x[n * 3 + 0] * base;
    const float a1 = pvs_l[64 + t]  - x[n * 3 + 1] * base;
    const float a2 = pvs_l[128 + t] - x[n * 3 + 2] * base;
    av_l[t * 3 + 0] = a0; av_l[t * 3 + 1] = a1; av_l[t * 3 + 2] = a2;
    inv_l[t] = a0 * a0 + a1 * a1 + a2 * a2;
  }
  __syncthreads();

  // hs partials: 4-way split over K
  {
    const int f = t & 127, part = t >> 7;
    float acc = 0.f;
    const float* wp = Wss + (part * 32) * FF + f;
    #pragma unroll 8
    for (int kk = 0; kk < 32; ++kk) acc += as_l[part * 32 + kk] * wp[kk * FF];
    const float* vp = Wvs + (part * 16) * FF + f;
    #pragma unroll 8
    for (int vv = 0; vv < 16; ++vv) acc += inv_l[part * 16 + vv] * vp[vv * FF];
    red[part * 128 + f] = acc;
  }
  __syncthreads();

  if (t < FF) {
    hsn[t] = silu_f(hs[n * FF + t] + red[t] + red[128 + t] + red[256 + t] + red[384 + t]);
  }
  if (t < 384) {
    const int part = t / 192, j = t - part * 192;
    const int wv = j / 3, d = j - wv * 3;
    float acc = 0.f;
    const float* vp = Wvv + (part * 32) * VV + wv;
    #pragma unroll 8
    for (int v = 0; v < 32; ++v) acc += av_l[(part * 32 + v) * 3 + d] * vp[v * VV];
    red2[part * 192 + j] = acc;
  }
  __syncthreads();

  if (t < 192) hv_l[t] = hv[n * 192 + t] + red2[t] + red2[192 + t];
  __syncthreads();

  // ---- readout (verified R11), inputs hsn / hv_l ----
  {
    const int f = t & 127, part = t >> 7;
    float acc = 0.f;
    const float* wp = Wro_s1 + (part * 32) * FF + f;
    #pragma unroll 8
    for (int kk = 0; kk < 32; ++kk) acc += hsn[part * 32 + kk] * wp[kk * FF];
    red[part * 128 + f] = acc;
  }
  __syncthreads();
  if (t < FF) t1[t] = silu_f(red[t] + red[128 + t] + red[256 + t] + red[384 + t]);
  if (t < 384) {
    const int part = t / 192, j = t - part * 192;
    const int wv = j / 3, d = j - wv * 3;
    float acc = 0.f;
    const float* vp = Wro_v1 + (part * 32) * VV + wv;
    #pragma unroll 8
    for (int v = 0; v < 32; ++v) acc += hv_l[(part * 32 + v) * 3 + d] * vp[v * VV];
    red2[part * 192 + j] = acc;
  }
  __syncthreads();
  if (t < 192) tv1[t] = red2[t] + red2[192 + t];
  if (t < 256) {
    const int o = t & 63, part = t >> 6;
    float acc = 0.f;
    const float* wp = Wro_s2 + (part * 32) * 64 + o;
    #pragma unroll 8
    for (int f = 0; f < 32; ++f) acc += t1[part * 32 + f] * wp[f * 64];
    red[t] = acc;
  }
  __syncthreads();
  if (t < 64) out[n * 160 + t] = red[t] + red[64 + t] + red[128 + t] + red[192 + t];
  if (t < 192) {
    const int part = t / 96, j = t - part * 96;
    const int w2 = j / 3, d = j - w2 * 3;
    float acc = 0.f;
    const float* vp = Wro_v2 + (part * 32) * 32 + w2;
    #pragma unroll 8
    for (int wv = 0; wv < 32; ++wv) acc += tv1[(part * 32 + wv) * 3 + d] * vp[wv * 32];
    red2[part * 96 + j] = acc;
  }
  __syncthreads();
  if (t < 96) out[n * 160 + 64 + t] = red2[t] + red2[96 + t];
}

// ---------------------------------------------------------------------------
extern "C" void kernel_launch(void* const* d_in, const int* in_sizes, int n_in,
                              void* d_out, int out_size, void* d_ws, size_t ws_size,
                              hipStream_t stream) {
  const float* x      = (const float*)d_in[0];
  const float* embed  = (const float*)d_in[3];
  const float* Wr1    = (const float*)d_in[4];   // [2][1][16]
  const float* Wr2s   = (const float*)d_in[5];   // [2][16][128]
  const float* Wr2v   = (const float*)d_in[6];   // [2][16][64]
  const float* Wsv    = (const float*)d_in[7];   // [2][128][64]
  const float* Wss    = (const float*)d_in[8];   // [2][128][128]
  const float* Wvs    = (const float*)d_in[9];   // [2][64][128]
  const float* Wvv    = (const float*)d_in[10];  // [2][64][64]
  const float* Wro_s1 = (const float*)d_in[11];
  const float* Wro_s2 = (const float*)d_in[12];
  const float* Wro_v1 = (const float*)d_in[13];
  const float* Wro_v2 = (const float*)d_in[14];

  float* ws_f = (float*)d_ws;
  float* hs    = ws_f;                      // 768*128
  float* hsv   = hs + NN * FF;              // 768*64
  float* hv    = hsv + NN * VV;             // 768*192
  float* Ps    = hv + NN * 192;             // 24*768*128
  float* Pv    = Ps + (size_t)SPLITK * NN * FF;   // 24*768*256
  unsigned short* Bs = (unsigned short*)(Pv + (size_t)SPLITK * NN * 256);
  unsigned short* Bv = Bs + (size_t)12288 * 128;
  float* out = (float*)d_out;

  // layer 0 (closed form) + node0, fused
  layer0_kernel<<<NN, 256, 0, stream>>>(
      x, Wr1, Wr2s, Wr2v, embed, Wsv, Wss, Wvs, Wvv, Wsv + FF * VV,
      hs, hsv, hv);

  // layer 1: B prep -> combined-kind MFMA edge GEMM -> node1+readout fused
  prep_kernel<<<2304, 256, 0, stream>>>(
      hs, hsv, x, Wr2s + RH * FF, Wr2v + RH * VV, Bs, Bv);
  edge_gemm<<<MB_N * SPLITK, 256, 0, stream>>>(
      x, Bs, Bv, Wr1 + RH, Ps, Pv);
  final_kernel<<<NN, 512, 0, stream>>>(
      Ps, Pv, x, hs, hv, Wss + FF * FF, Wvs + VV * FF, Wvv + VV * VV,
      Wro_s1, Wro_s2, Wro_v1, Wro_v2, out);
}

// Round 13
// 61.122 us; speedup vs baseline: 3.1089x; 1.0650x over previous
//
#include <hip/hip_runtime.h>
#include <hip/hip_bf16.h>
#include <math.h>

#define NN 768
#define FF 128
#define VV 64
#define RH 16
#define SPLITK 24
#define SEND_PER_KC 32          // 768 / SPLITK
#define NITER 4                 // SEND_PER_KC / 8 senders per iter
#define KSTEPS 384              // 12288 / 32
#define NT_S 8                  // scalar n-tiles (128/16)
#define NT_V 16                 // vector n-tiles (256/16)
#define MB_N 24                 // M-blocks (768/32)
#define CHUNK 256
#define RPAD 260                // 256 + 4 pad: row stride % 32 = 4 -> 2-way max

typedef __attribute__((ext_vector_type(8))) short bf16x8_t;
typedef __attribute__((ext_vector_type(4))) float f32x4;

__device__ __forceinline__ float silu_f(float a) {
  return a * __builtin_amdgcn_rcpf(1.0f + __expf(-a));
}

__device__ __forceinline__ short f2bf(float f) {
  __hip_bfloat16 h = __float2bfloat16(f);  // RNE; pairs into v_cvt_pk_bf16_f32
  return __builtin_bit_cast(short, h);
}

__device__ __forceinline__ float bf2f(unsigned short v) {
  return __builtin_bit_cast(float, (unsigned)v << 16);
}

// ---------------------------------------------------------------------------
// Layer-0 fused kernel (R12 verbatim): closed-form edge pass + node update.
// ---------------------------------------------------------------------------
__global__ __launch_bounds__(256) void layer0_kernel(
    const float* __restrict__ x,
    const float* __restrict__ Wr1,    // [16] layer-0
    const float* __restrict__ Wr2s,   // [16][128] layer-0
    const float* __restrict__ Wr2v,   // [16][64]  layer-0
    const float* __restrict__ embed,  // [128]
    const float* __restrict__ Wsv0,   // [128][64] layer-0
    const float* __restrict__ Wss,    // [128][128] layer-0
    const float* __restrict__ Wvs,    // [64][128]  layer-0
    const float* __restrict__ Wvv,    // [64][64]   layer-0
    const float* __restrict__ Wsv1,   // [128][64]  layer-1 (for hsv)
    float* __restrict__ hs,
    float* __restrict__ hsv,
    float* __restrict__ hv)
{
  __shared__ float rf_t[RH * RPAD];   // [h][sender]
  __shared__ float u_t[4 * RPAD];     // [{ux,uy,uz,1}][sender]
  __shared__ float red[4][64];
  __shared__ float fin[64];
  __shared__ float cvs[64];
  __shared__ float as_l[FF];
  __shared__ float av_l[192];
  __shared__ float inv_l[VV];
  __shared__ float hsn[FF];
  __shared__ float redn[256];

  const int r   = blockIdx.x;
  const int tid = threadIdx.x;
  const int j   = tid & 63;   // output index: h*4 + c
  const int q   = tid >> 6;   // sender quarter
  const int h   = j >> 2;
  const int c   = j & 3;
  const int sel = (c + 3) & 3;  // c==0 -> ones row (R); else u row c-1 (T)

  // c[v] = embed @ Wsv0
  if (tid < 64) {
    float a = 0.f;
    #pragma unroll 8
    for (int f = 0; f < FF; ++f) a += embed[f] * Wsv0[f * VV + tid];
    cvs[tid] = a;
  }

  float wr1[RH];
  #pragma unroll
  for (int hh = 0; hh < RH; ++hh) wr1[hh] = Wr1[hh];

  const float xr0 = x[r * 3 + 0], xr1 = x[r * 3 + 1], xr2 = x[r * 3 + 2];

  float acc = 0.f;
  for (int cb = 0; cb < NN; cb += CHUNK) {
    // phase 1: thread = sender cb+tid (x is L1-resident, 9 KB)
    {
      const int s = cb + tid;
      const float vx = x[s * 3 + 0] - xr0;
      const float vy = x[s * 3 + 1] - xr1;
      const float vz = x[s * 3 + 2] - xr2;
      const float d  = __builtin_amdgcn_sqrtf(vx * vx + vy * vy + vz * vz);
      const float iv = __builtin_amdgcn_rcpf(d + 1e-8f);
      u_t[0 * RPAD + tid] = vx * iv;
      u_t[1 * RPAD + tid] = vy * iv;
      u_t[2 * RPAD + tid] = vz * iv;
      u_t[3 * RPAD + tid] = 1.0f;
      #pragma unroll
      for (int hh = 0; hh < RH; ++hh)
        rf_t[hh * RPAD + tid] = silu_f(d * wr1[hh]);
    }
    __syncthreads();

    // phase 2: float4 over 4 senders per step
    const float* rp = &rf_t[h * RPAD + q * 64];
    const float* up = &u_t[sel * RPAD + q * 64];
    #pragma unroll 8
    for (int si = 0; si < 64; si += 4) {
      const float4 ra = *(const float4*)&rp[si];
      const float4 ua = *(const float4*)&up[si];
      acc += ra.x * ua.x + ra.y * ua.y + ra.z * ua.z + ra.w * ua.w;
    }
    __syncthreads();
  }

  red[q][j] = acc;
  __syncthreads();
  if (tid < 64) fin[tid] = red[0][tid] + red[1][tid] + red[2][tid] + red[3][tid];
  __syncthreads();

  // agg into LDS (no global round trip)
  if (tid < FF) {
    float a = 0.f;
    #pragma unroll
    for (int hh = 0; hh < RH; ++hh) a += fin[hh * 4] * Wr2s[hh * FF + tid];
    as_l[tid] = a * embed[tid] * (1.0f / 64.0f);
  }
  if (tid < 192) {
    const int v = tid / 3, d = tid - v * 3;
    float a = 0.f;
    #pragma unroll
    for (int hh = 0; hh < RH; ++hh) a += fin[hh * 4 + 1 + d] * Wr2v[hh * VV + v];
    av_l[tid] = a * cvs[v] * (1.0f / 64.0f);
  }
  __syncthreads();

  if (tid < VV) {
    const float a0 = av_l[tid * 3 + 0], a1 = av_l[tid * 3 + 1], a2 = av_l[tid * 3 + 2];
    inv_l[tid] = a0 * a0 + a1 * a1 + a2 * a2;
  }
  __syncthreads();

  // hs partials: 2-way K split over 256 threads
  {
    const int f = tid & 127, part = tid >> 7;   // 0/1
    float a = 0.f;
    const float* wp = Wss + (part * 64) * FF + f;
    #pragma unroll 8
    for (int kk = 0; kk < 64; ++kk) a += as_l[part * 64 + kk] * wp[kk * FF];
    const float* vp = Wvs + (part * 32) * FF + f;
    #pragma unroll 8
    for (int vv = 0; vv < 32; ++vv) a += inv_l[part * 32 + vv] * vp[vv * FF];
    redn[part * 128 + f] = a;
  }
  __syncthreads();

  if (tid < FF) {
    const float hnew = silu_f(embed[tid] + redn[tid] + redn[128 + tid]);
    hs[(size_t)r * FF + tid] = hnew;
    hsn[tid] = hnew;
  }
  // hv = av @ Wvv (hv_prev = 0)
  if (tid < 192) {
    const int w = tid / 3, d = tid - w * 3;
    float a = 0.f;
    #pragma unroll 8
    for (int v = 0; v < VV; ++v) a += av_l[v * 3 + d] * Wvv[v * VV + w];
    hv[(size_t)r * 192 + tid] = a;
  }
  __syncthreads();

  // hsv = hsn @ Wsv1 : 4-way split
  {
    const int v = tid & 63, part = tid >> 6;   // 0..3
    float a = 0.f;
    const float* wp = Wsv1 + (part * 32) * VV + v;
    #pragma unroll 8
    for (int f = 0; f < 32; ++f) a += hsn[part * 32 + f] * wp[f * VV];
    redn[tid] = a;
  }
  __syncthreads();
  if (tid < VV)
    hsv[(size_t)r * VV + tid] = redn[tid] + redn[64 + tid] + redn[128 + tid] + redn[192 + tid];
}

// ---------------------------------------------------------------------------
// prep: build B matrices in MFMA-fragment-major layout (bf16). (verified)
// ---------------------------------------------------------------------------
__global__ __launch_bounds__(256) void prep_kernel(
    const float* __restrict__ hs, const float* __restrict__ hsv,
    const float* __restrict__ x,
    const float* __restrict__ Wr2s,   // [16][128] layer-1 slice
    const float* __restrict__ Wr2v,   // [16][64]  layer-1 slice
    unsigned short* __restrict__ Bs, unsigned short* __restrict__ Bv)
{
  const int gid   = blockIdx.x * 256 + threadIdx.x;
  const int lane  = gid & 63;
  const int tmp   = gid >> 6;
  const int ntile = tmp % 24;
  const int kstep = tmp / 24;
  if (kstep >= KSTEPS) return;
  const int qq = lane >> 4;              // octet index 0..3
  const int s  = kstep * 2 + (qq >> 1);
  const int hb = (qq & 1) * 8;

  bf16x8_t o;
  if (ntile < NT_S) {
    const int f = ntile * 16 + (lane & 15);
    const float hf = hs[s * FF + f] * 0.015625f;
    #pragma unroll
    for (int e = 0; e < 8; ++e)
      o[e] = f2bf(hf * Wr2s[(hb + e) * FF + f]);
    *(bf16x8_t*)&Bs[((size_t)(kstep * NT_S + ntile) * 64 + lane) * 8] = o;
  } else {
    const int nt2 = ntile - NT_S;
    const int n   = nt2 * 16 + (lane & 15);
    int v; float scale;
    if (n < 192) { const int dd = n >> 6; v = n & 63;
                   scale = x[s * 3 + dd] * hsv[s * VV + v] * 0.015625f; }
    else         { v = n - 192; scale = hsv[s * VV + v] * 0.015625f; }
    #pragma unroll
    for (int e = 0; e < 8; ++e)
      o[e] = f2bf(scale * Wr2v[(hb + e) * VV + v]);
    *(bf16x8_t*)&Bv[((size_t)(kstep * NT_V + nt2) * 64 + lane) * 8] = o;
  }
}

// ---------------------------------------------------------------------------
// edge GEMM v7 (R12 verbatim, bf16 partial output): M=32/block, 4 waves,
// grid = 24 mb x 24 kc = 576. silu chain ONCE per (r,s); A_lds + G_lds.
// ---------------------------------------------------------------------------
__global__ __launch_bounds__(256) void edge_gemm(
    const float* __restrict__ x,
    const unsigned short* __restrict__ Bs,
    const unsigned short* __restrict__ Bv,
    const float* __restrict__ Wr1,    // [16] layer-1 slice
    unsigned short* __restrict__ Ps,  // [SPLITK][768][128] bf16
    unsigned short* __restrict__ Pv)  // [SPLITK][768][256] bf16
{
  __shared__ unsigned short A_lds[4 * 2 * 64 * 8];  // 8 KB scalar A
  __shared__ unsigned short G_lds[4 * 2 * 64 * 8];  // 8 KB vector A (rf*iv)

  // bijective XCD swizzle: 576 = 8 * 72; xcd owns kc in [3*xcd, 3*xcd+2]
  const int wg = ((blockIdx.x & 7) * 72) + (blockIdx.x >> 3);
  const int kc = wg / MB_N;
  const int mb = wg - kc * MB_N;

  const int tid  = threadIdx.x;
  const int lane = tid & 63;
  const int w    = tid >> 6;

  float wr1[RH];
  #pragma unroll
  for (int h = 0; h < RH; ++h) wr1[h] = Wr1[h];

  const int r_local = tid & 31;
  const int s_ii    = tid >> 5;        // 0..7
  const int r = mb * 32 + r_local;
  const int mt_w  = r_local >> 4;
  const int ks_w  = s_ii >> 1;
  const int lane0 = (r_local & 15) + ((s_ii & 1) << 5);

  const float xr0 = x[r * 3 + 0], xr1 = x[r * 3 + 1], xr2 = x[r * 3 + 2];
  float sx[NITER], sy[NITER], sz[NITER];
  #pragma unroll
  for (int it = 0; it < NITER; ++it) {
    const int s = kc * SEND_PER_KC + it * 8 + s_ii;
    sx[it] = x[s * 3 + 0]; sy[it] = x[s * 3 + 1]; sz[it] = x[s * 3 + 2];
  }

  f32x4 accS[4], accV[8];
  #pragma unroll
  for (int i = 0; i < 4; ++i) accS[i] = (f32x4){0.f, 0.f, 0.f, 0.f};
  #pragma unroll
  for (int i = 0; i < 8; ++i) accV[i] = (f32x4){0.f, 0.f, 0.f, 0.f};

  for (int it = 0; it < NITER; ++it) {
    // ---- A generation: silu chain ONCE, two LDS images ----
    {
      const float vx = sx[it] - xr0;
      const float vy = sy[it] - xr1;
      const float vz = sz[it] - xr2;
      const float dd = __builtin_amdgcn_sqrtf(vx * vx + vy * vy + vz * vz);
      const float iv = __builtin_amdgcn_rcpf(dd + 1e-8f);
      float sv[RH];
      #pragma unroll
      for (int h = 0; h < RH; ++h) sv[h] = silu_f(dd * wr1[h]);
      bf16x8_t o0, o1, g0, g1;
      #pragma unroll
      for (int h = 0; h < 8; ++h) {
        o0[h] = f2bf(sv[h]);
        o1[h] = f2bf(sv[h + 8]);
        g0[h] = f2bf(sv[h] * iv);
        g1[h] = f2bf(sv[h + 8] * iv);
      }
      const int off0 = ((ks_w * 2 + mt_w) * 64 + lane0) * 8;
      *(bf16x8_t*)&A_lds[off0]       = o0;
      *(bf16x8_t*)&A_lds[off0 + 128] = o1;   // +16 lanes * 8
      *(bf16x8_t*)&G_lds[off0]       = g0;
      *(bf16x8_t*)&G_lds[off0 + 128] = g1;
    }
    __syncthreads();

    // ---- MFMA: scalar (2 nt) + vector (4 nt) per wave ----
    const int kgb = kc * (SEND_PER_KC / 2) + it * 4;
    #pragma unroll
    for (int ks = 0; ks < 4; ++ks) {
      const bf16x8_t b0 =
          *(const bf16x8_t*)&Bs[((size_t)((kgb + ks) * NT_S + 2 * w) * 64 + lane) * 8];
      const bf16x8_t b1 =
          *(const bf16x8_t*)&Bs[((size_t)((kgb + ks) * NT_S + 2 * w + 1) * 64 + lane) * 8];
      bf16x8_t bv[4];
      #pragma unroll
      for (int j = 0; j < 4; ++j)
        bv[j] = *(const bf16x8_t*)&Bv[((size_t)((kgb + ks) * NT_V + 4 * w + j) * 64 + lane) * 8];
      #pragma unroll
      for (int mt = 0; mt < 2; ++mt) {
        const int aoff = ((ks * 2 + mt) * 64 + lane) * 8;
        const bf16x8_t a  = *(const bf16x8_t*)&A_lds[aoff];
        const bf16x8_t ag = *(const bf16x8_t*)&G_lds[aoff];
        accS[mt * 2 + 0] = __builtin_amdgcn_mfma_f32_16x16x32_bf16(a, b0, accS[mt * 2 + 0], 0, 0, 0);
        accS[mt * 2 + 1] = __builtin_amdgcn_mfma_f32_16x16x32_bf16(a, b1, accS[mt * 2 + 1], 0, 0, 0);
        #pragma unroll
        for (int j = 0; j < 4; ++j)
          accV[mt * 4 + j] = __builtin_amdgcn_mfma_f32_16x16x32_bf16(ag, bv[j], accV[mt * 4 + j], 0, 0, 0);
      }
    }
    __syncthreads();
  }

  // ---- epilogue: write bf16 partials (each element written exactly once) ----
  const int rowq = (lane >> 4) << 2;
  #pragma unroll
  for (int j = 0; j < 2; ++j) {
    const int col = (2 * w + j) * 16 + (lane & 15);
    #pragma unroll
    for (int mt = 0; mt < 2; ++mt) {
      #pragma unroll
      for (int reg = 0; reg < 4; ++reg) {
        const int row = mb * 32 + mt * 16 + rowq + reg;
        Ps[((size_t)kc * NN + row) * FF + col] =
            (unsigned short)f2bf(accS[mt * 2 + j][reg]);
      }
    }
  }
  #pragma unroll
  for (int j = 0; j < 4; ++j) {
    const int col = (4 * w + j) * 16 + (lane & 15);
    #pragma unroll
    for (int mt = 0; mt < 2; ++mt) {
      #pragma unroll
      for (int reg = 0; reg < 4; ++reg) {
        const int row = mb * 32 + mt * 16 + rowq + reg;
        Pv[((size_t)kc * NN + row) * 256 + col] =
            (unsigned short)f2bf(accV[mt * 4 + j][reg]);
      }
    }
  }
}

// ---------------------------------------------------------------------------
// final kernel (R12 structure, bf16 partial input): node1 + readout fused.
// ---------------------------------------------------------------------------
__global__ __launch_bounds__(512) void final_kernel(
    const unsigned short* __restrict__ Ps,  // [SPLITK][768][128] bf16
    const unsigned short* __restrict__ Pv,  // [SPLITK][768][256] bf16
    const float* __restrict__ x,
    const float* __restrict__ hs,       // layer-0 output
    const float* __restrict__ hv,       // layer-0 output
    const float* __restrict__ Wss,      // layer-1
    const float* __restrict__ Wvs,      // layer-1
    const float* __restrict__ Wvv,      // layer-1
    const float* __restrict__ Wro_s1,
    const float* __restrict__ Wro_s2,
    const float* __restrict__ Wro_v1,
    const float* __restrict__ Wro_v2,
    float* __restrict__ out)
{
  __shared__ float as_l[FF];
  __shared__ float pvs_l[256];
  __shared__ float av_l[192];
  __shared__ float inv_l[VV];
  __shared__ float hsn[FF];
  __shared__ float hv_l[192];
  __shared__ float red[512];
  __shared__ float red2[384];
  __shared__ float t1[FF];
  __shared__ float tv1[192];
  const int n = blockIdx.x, t = threadIdx.x;

  // fused splitK reduce (bf16 loads)
  if (t < FF) {
    float a = 0.f;
    #pragma unroll
    for (int kc = 0; kc < SPLITK; ++kc)
      a += bf2f(Ps[((size_t)kc * NN + n) * FF + t]);
    as_l[t] = a;
  } else if (t < 384) {
    const int cc = t - 128;
    float a = 0.f;
    #pragma unroll
    for (int kc = 0; kc < SPLITK; ++kc)
      a += bf2f(Pv[((size_t)kc * NN + n) * 256 + cc]);
    pvs_l[cc] = a;
  }
  __syncthreads();

  if (t < VV) {
    const float base = pvs_l[192 + t];
    const float a0 = pvs_l[t]       - x[n * 3 + 0] * base;
    const float a1 = pvs_l[64 + t]  - x[n * 3 + 1] * base;
    const float a2 = pvs_l[128 + t] - x[n * 3 + 2] * base;
    av_l[t * 3 + 0] = a0; av_l[t * 3 + 1] = a1; av_l[t * 3 + 2] = a2;
    inv_l[t] = a0 * a0 + a1 * a1 + a2 * a2;
  }
  __syncthreads();

  // hs partials: 4-way split over K
  {
    const int f = t & 127, part = t >> 7;
    float acc = 0.f;
    const float* wp = Wss + (part * 32) * FF + f;
    #pragma unroll 8
    for (int kk = 0; kk < 32; ++kk) acc += as_l[part * 32 + kk] * wp[kk * FF];
    const float* vp = Wvs + (part * 16) * FF + f;
    #pragma unroll 8
    for (int vv = 0; vv < 16; ++vv) acc += inv_l[part * 16 + vv] * vp[vv * FF];
    red[part * 128 + f] = acc;
  }
  __syncthreads();

  if (t < FF) {
    hsn[t] = silu_f(hs[n * FF + t] + red[t] + red[128 + t] + red[256 + t] + red[384 + t]);
  }
  if (t < 384) {
    const int part = t / 192, j = t - part * 192;
    const int wv = j / 3, d = j - wv * 3;
    float acc = 0.f;
    const float* vp = Wvv + (part * 32) * VV + wv;
    #pragma unroll 8
    for (int v = 0; v < 32; ++v) acc += av_l[(part * 32 + v) * 3 + d] * vp[v * VV];
    red2[part * 192 + j] = acc;
  }
  __syncthreads();

  if (t < 192) hv_l[t] = hv[n * 192 + t] + red2[t] + red2[192 + t];
  __syncthreads();

  // ---- readout, inputs hsn / hv_l ----
  {
    const int f = t & 127, part = t >> 7;
    float acc = 0.f;
    const float* wp = Wro_s1 + (part * 32) * FF + f;
    #pragma unroll 8
    for (int kk = 0; kk < 32; ++kk) acc += hsn[part * 32 + kk] * wp[kk * FF];
    red[part * 128 + f] = acc;
  }
  __syncthreads();
  if (t < FF) t1[t] = silu_f(red[t] + red[128 + t] + red[256 + t] + red[384 + t]);
  if (t < 384) {
    const int part = t / 192, j = t - part * 192;
    const int wv = j / 3, d = j - wv * 3;
    float acc = 0.f;
    const float* vp = Wro_v1 + (part * 32) * VV + wv;
    #pragma unroll 8
    for (int v = 0; v < 32; ++v) acc += hv_l[(part * 32 + v) * 3 + d] * vp[v * VV];
    red2[part * 192 + j] = acc;
  }
  __syncthreads();
  if (t < 192) tv1[t] = red2[t] + red2[192 + t];
  if (t < 256) {
    const int o = t & 63, part = t >> 6;
    float acc = 0.f;
    const float* wp = Wro_s2 + (part * 32) * 64 + o;
    #pragma unroll 8
    for (int f = 0; f < 32; ++f) acc += t1[part * 32 + f] * wp[f * 64];
    red[t] = acc;
  }
  __syncthreads();
  if (t < 64) out[n * 160 + t] = red[t] + red[64 + t] + red[128 + t] + red[192 + t];
  if (t < 192) {
    const int part = t / 96, j = t - part * 96;
    const int w2 = j / 3, d = j - w2 * 3;
    float acc = 0.f;
    const float* vp = Wro_v2 + (part * 32) * 32 + w2;
    #pragma unroll 8
    for (int wv = 0; wv < 32; ++wv) acc += tv1[(part * 32 + wv) * 3 + d] * vp[wv * 32];
    red2[part * 96 + j] = acc;
  }
  __syncthreads();
  if (t < 96) out[n * 160 + 64 + t] = red2[t] + red2[96 + t];
}

// ---------------------------------------------------------------------------
extern "C" void kernel_launch(void* const* d_in, const int* in_sizes, int n_in,
                              void* d_out, int out_size, void* d_ws, size_t ws_size,
                              hipStream_t stream) {
  const float* x      = (const float*)d_in[0];
  const float* embed  = (const float*)d_in[3];
  const float* Wr1    = (const float*)d_in[4];   // [2][1][16]
  const float* Wr2s   = (const float*)d_in[5];   // [2][16][128]
  const float* Wr2v   = (const float*)d_in[6];   // [2][16][64]
  const float* Wsv    = (const float*)d_in[7];   // [2][128][64]
  const float* Wss    = (const float*)d_in[8];   // [2][128][128]
  const float* Wvs    = (const float*)d_in[9];   // [2][64][128]
  const float* Wvv    = (const float*)d_in[10];  // [2][64][64]
  const float* Wro_s1 = (const float*)d_in[11];
  const float* Wro_s2 = (const float*)d_in[12];
  const float* Wro_v1 = (const float*)d_in[13];
  const float* Wro_v2 = (const float*)d_in[14];

  float* ws_f = (float*)d_ws;
  float* hs    = ws_f;                      // 768*128 f32
  float* hsv   = hs + NN * FF;              // 768*64  f32
  float* hv    = hsv + NN * VV;             // 768*192 f32
  unsigned short* Ps = (unsigned short*)(hv + NN * 192);       // 24*768*128 bf16
  unsigned short* Pv = Ps + (size_t)SPLITK * NN * FF;          // 24*768*256 bf16
  unsigned short* Bs = Pv + (size_t)SPLITK * NN * 256;         // 12288*128 bf16
  unsigned short* Bv = Bs + (size_t)12288 * 128;               // 12288*256 bf16
  float* out = (float*)d_out;

  // layer 0 (closed form) + node0, fused
  layer0_kernel<<<NN, 256, 0, stream>>>(
      x, Wr1, Wr2s, Wr2v, embed, Wsv, Wss, Wvs, Wvv, Wsv + FF * VV,
      hs, hsv, hv);

  // layer 1: B prep -> combined-kind MFMA edge GEMM -> node1+readout fused
  prep_kernel<<<2304, 256, 0, stream>>>(
      hs, hsv, x, Wr2s + RH * FF, Wr2v + RH * VV, Bs, Bv);
  edge_gemm<<<MB_N * SPLITK, 256, 0, stream>>>(
      x, Bs, Bv, Wr1 + RH, Ps, Pv);
  final_kernel<<<NN, 512, 0, stream>>>(
      Ps, Pv, x, hs, hv, Wss + FF * FF, Wvs + VV * FF, Wvv + VV * VV,
      Wro_s1, Wro_s2, Wro_v1, Wro_v2, out);
}

// Round 14
// 58.771 us; speedup vs baseline: 3.2332x; 1.0400x over previous
//
#include <hip/hip_runtime.h>
#include <hip/hip_bf16.h>
#include <math.h>

#define NN 768
#define FF 128
#define VV 64
#define RH 16
#define SPLITK 24
#define SEND_PER_KC 32          // 768 / SPLITK
#define NITER 4                 // SEND_PER_KC / 8 senders per iter
#define KSTEPS 384              // 12288 / 32
#define NT_S 8                  // scalar n-tiles (128/16)
#define NT_V 16                 // vector n-tiles (256/16)
#define MB_N 24                 // M-blocks (768/32)

typedef __attribute__((ext_vector_type(8))) short bf16x8_t;
typedef __attribute__((ext_vector_type(4))) float f32x4;

__device__ __forceinline__ float silu_f(float a) {
  return a * __builtin_amdgcn_rcpf(1.0f + __expf(-a));
}

__device__ __forceinline__ short f2bf(float f) {
  __hip_bfloat16 h = __float2bfloat16(f);  // RNE; pairs into v_cvt_pk_bf16_f32
  return __builtin_bit_cast(short, h);
}

__device__ __forceinline__ float bf2f(unsigned short v) {
  return __builtin_bit_cast(float, (unsigned)v << 16);
}

// ---------------------------------------------------------------------------
// Layer-0 fused kernel v2: register-resident moments + node update.
// One block per receiver r, 256 threads. Thread owns senders tid+256*ss
// (ss=0..2): d/u/rf in registers, 64 statically-indexed accumulators
// acc[h*4+c] += rf[h]*{1,ux,uy,uz}. NO LDS/barriers in the main loop.
// Final: 256x64 transpose-reduce via LDS, two 33-pitch rounds
// (bank = (t+i)%32 -> worst 2-way, free). Then R12/R13-verbatim node tail.
// ---------------------------------------------------------------------------
__global__ __launch_bounds__(256) void layer0_kernel(
    const float* __restrict__ x,
    const float* __restrict__ Wr1,    // [16] layer-0
    const float* __restrict__ Wr2s,   // [16][128] layer-0
    const float* __restrict__ Wr2v,   // [16][64]  layer-0
    const float* __restrict__ embed,  // [128]
    const float* __restrict__ Wsv0,   // [128][64] layer-0
    const float* __restrict__ Wss,    // [128][128] layer-0
    const float* __restrict__ Wvs,    // [64][128]  layer-0
    const float* __restrict__ Wvv,    // [64][64]   layer-0
    const float* __restrict__ Wsv1,   // [128][64]  layer-1 (for hsv)
    float* __restrict__ hs,
    float* __restrict__ hsv,
    float* __restrict__ hv)
{
  __shared__ float accT[256 * 33];    // 33.8 KB transpose-reduce scratch
  __shared__ float red8[8][32];
  __shared__ float fin[64];
  __shared__ float cvs[64];
  __shared__ float as_l[FF];
  __shared__ float av_l[192];
  __shared__ float inv_l[VV];
  __shared__ float hsn[FF];
  __shared__ float redn[256];

  const int r   = blockIdx.x;
  const int tid = threadIdx.x;

  // c[v] = embed @ Wsv0 (consumed after the reduce barriers)
  if (tid < 64) {
    float a = 0.f;
    #pragma unroll 8
    for (int f = 0; f < FF; ++f) a += embed[f] * Wsv0[f * VV + tid];
    cvs[tid] = a;
  }

  float wr1[RH];
  #pragma unroll
  for (int hh = 0; hh < RH; ++hh) wr1[hh] = Wr1[hh];

  const float xr0 = x[r * 3 + 0], xr1 = x[r * 3 + 1], xr2 = x[r * 3 + 2];

  float acc[64];
  #pragma unroll
  for (int i = 0; i < 64; ++i) acc[i] = 0.f;

  // ---- main loop: 3 senders per thread, all in registers ----
  #pragma unroll
  for (int ss = 0; ss < 3; ++ss) {
    const int s = tid + ss * 256;
    const float vx = x[s * 3 + 0] - xr0;
    const float vy = x[s * 3 + 1] - xr1;
    const float vz = x[s * 3 + 2] - xr2;
    const float d  = __builtin_amdgcn_sqrtf(vx * vx + vy * vy + vz * vz);
    const float iv = __builtin_amdgcn_rcpf(d + 1e-8f);
    const float ux = vx * iv, uy = vy * iv, uz = vz * iv;
    #pragma unroll
    for (int h = 0; h < RH; ++h) {
      const float rf = silu_f(d * wr1[h]);
      acc[h * 4 + 0] += rf;
      acc[h * 4 + 1] += rf * ux;
      acc[h * 4 + 2] += rf * uy;
      acc[h * 4 + 3] += rf * uz;
    }
  }

  // ---- transpose-reduce: round A (j 0..31), round B (j 32..63) ----
  {
    #pragma unroll
    for (int i = 0; i < 32; ++i) accT[tid * 33 + i] = acc[i];
    __syncthreads();
    {
      const int j2 = tid & 31, q2 = tid >> 5;
      float a0 = 0.f, a1 = 0.f;
      #pragma unroll 8
      for (int rr = 0; rr < 32; rr += 2) {
        a0 += accT[(q2 * 32 + rr) * 33 + j2];
        a1 += accT[(q2 * 32 + rr + 1) * 33 + j2];
      }
      red8[q2][j2] = a0 + a1;
    }
    __syncthreads();
    if (tid < 32) {
      float a = 0.f;
      #pragma unroll
      for (int g = 0; g < 8; ++g) a += red8[g][tid];
      fin[tid] = a;
    }
    __syncthreads();

    #pragma unroll
    for (int i = 0; i < 32; ++i) accT[tid * 33 + i] = acc[32 + i];
    __syncthreads();
    {
      const int j2 = tid & 31, q2 = tid >> 5;
      float a0 = 0.f, a1 = 0.f;
      #pragma unroll 8
      for (int rr = 0; rr < 32; rr += 2) {
        a0 += accT[(q2 * 32 + rr) * 33 + j2];
        a1 += accT[(q2 * 32 + rr + 1) * 33 + j2];
      }
      red8[q2][j2] = a0 + a1;
    }
    __syncthreads();
    if (tid < 32) {
      float a = 0.f;
      #pragma unroll
      for (int g = 0; g < 8; ++g) a += red8[g][tid];
      fin[32 + tid] = a;
    }
    __syncthreads();
  }

  // ---- node tail (R12/R13 verbatim): agg -> hs/hv/hsv ----
  if (tid < FF) {
    float a = 0.f;
    #pragma unroll
    for (int hh = 0; hh < RH; ++hh) a += fin[hh * 4] * Wr2s[hh * FF + tid];
    as_l[tid] = a * embed[tid] * (1.0f / 64.0f);
  }
  if (tid < 192) {
    const int v = tid / 3, d = tid - v * 3;
    float a = 0.f;
    #pragma unroll
    for (int hh = 0; hh < RH; ++hh) a += fin[hh * 4 + 1 + d] * Wr2v[hh * VV + v];
    av_l[tid] = a * cvs[v] * (1.0f / 64.0f);
  }
  __syncthreads();

  if (tid < VV) {
    const float a0 = av_l[tid * 3 + 0], a1 = av_l[tid * 3 + 1], a2 = av_l[tid * 3 + 2];
    inv_l[tid] = a0 * a0 + a1 * a1 + a2 * a2;
  }
  __syncthreads();

  // hs partials: 2-way K split over 256 threads
  {
    const int f = tid & 127, part = tid >> 7;   // 0/1
    float a = 0.f;
    const float* wp = Wss + (part * 64) * FF + f;
    #pragma unroll 8
    for (int kk = 0; kk < 64; ++kk) a += as_l[part * 64 + kk] * wp[kk * FF];
    const float* vp = Wvs + (part * 32) * FF + f;
    #pragma unroll 8
    for (int vv = 0; vv < 32; ++vv) a += inv_l[part * 32 + vv] * vp[vv * FF];
    redn[part * 128 + f] = a;
  }
  __syncthreads();

  if (tid < FF) {
    const float hnew = silu_f(embed[tid] + redn[tid] + redn[128 + tid]);
    hs[(size_t)r * FF + tid] = hnew;
    hsn[tid] = hnew;
  }
  // hv = av @ Wvv (hv_prev = 0)
  if (tid < 192) {
    const int w = tid / 3, d = tid - w * 3;
    float a = 0.f;
    #pragma unroll 8
    for (int v = 0; v < VV; ++v) a += av_l[v * 3 + d] * Wvv[v * VV + w];
    hv[(size_t)r * 192 + tid] = a;
  }
  __syncthreads();

  // hsv = hsn @ Wsv1 : 4-way split
  {
    const int v = tid & 63, part = tid >> 6;   // 0..3
    float a = 0.f;
    const float* wp = Wsv1 + (part * 32) * VV + v;
    #pragma unroll 8
    for (int f = 0; f < 32; ++f) a += hsn[part * 32 + f] * wp[f * VV];
    redn[tid] = a;
  }
  __syncthreads();
  if (tid < VV)
    hsv[(size_t)r * VV + tid] = redn[tid] + redn[64 + tid] + redn[128 + tid] + redn[192 + tid];
}

// ---------------------------------------------------------------------------
// prep: build B matrices in MFMA-fragment-major layout (bf16). (verified)
// ---------------------------------------------------------------------------
__global__ __launch_bounds__(256) void prep_kernel(
    const float* __restrict__ hs, const float* __restrict__ hsv,
    const float* __restrict__ x,
    const float* __restrict__ Wr2s,   // [16][128] layer-1 slice
    const float* __restrict__ Wr2v,   // [16][64]  layer-1 slice
    unsigned short* __restrict__ Bs, unsigned short* __restrict__ Bv)
{
  const int gid   = blockIdx.x * 256 + threadIdx.x;
  const int lane  = gid & 63;
  const int tmp   = gid >> 6;
  const int ntile = tmp % 24;
  const int kstep = tmp / 24;
  if (kstep >= KSTEPS) return;
  const int qq = lane >> 4;              // octet index 0..3
  const int s  = kstep * 2 + (qq >> 1);
  const int hb = (qq & 1) * 8;

  bf16x8_t o;
  if (ntile < NT_S) {
    const int f = ntile * 16 + (lane & 15);
    const float hf = hs[s * FF + f] * 0.015625f;
    #pragma unroll
    for (int e = 0; e < 8; ++e)
      o[e] = f2bf(hf * Wr2s[(hb + e) * FF + f]);
    *(bf16x8_t*)&Bs[((size_t)(kstep * NT_S + ntile) * 64 + lane) * 8] = o;
  } else {
    const int nt2 = ntile - NT_S;
    const int n   = nt2 * 16 + (lane & 15);
    int v; float scale;
    if (n < 192) { const int dd = n >> 6; v = n & 63;
                   scale = x[s * 3 + dd] * hsv[s * VV + v] * 0.015625f; }
    else         { v = n - 192; scale = hsv[s * VV + v] * 0.015625f; }
    #pragma unroll
    for (int e = 0; e < 8; ++e)
      o[e] = f2bf(scale * Wr2v[(hb + e) * VV + v]);
    *(bf16x8_t*)&Bv[((size_t)(kstep * NT_V + nt2) * 64 + lane) * 8] = o;
  }
}

// ---------------------------------------------------------------------------
// edge GEMM v7 (R13 verbatim, bf16 partial output): M=32/block, 4 waves,
// grid = 24 mb x 24 kc = 576. silu chain ONCE per (r,s); A_lds + G_lds.
// ---------------------------------------------------------------------------
__global__ __launch_bounds__(256) void edge_gemm(
    const float* __restrict__ x,
    const unsigned short* __restrict__ Bs,
    const unsigned short* __restrict__ Bv,
    const float* __restrict__ Wr1,    // [16] layer-1 slice
    unsigned short* __restrict__ Ps,  // [SPLITK][768][128] bf16
    unsigned short* __restrict__ Pv)  // [SPLITK][768][256] bf16
{
  __shared__ unsigned short A_lds[4 * 2 * 64 * 8];  // 8 KB scalar A
  __shared__ unsigned short G_lds[4 * 2 * 64 * 8];  // 8 KB vector A (rf*iv)

  // bijective XCD swizzle: 576 = 8 * 72; xcd owns kc in [3*xcd, 3*xcd+2]
  const int wg = ((blockIdx.x & 7) * 72) + (blockIdx.x >> 3);
  const int kc = wg / MB_N;
  const int mb = wg - kc * MB_N;

  const int tid  = threadIdx.x;
  const int lane = tid & 63;
  const int w    = tid >> 6;

  float wr1[RH];
  #pragma unroll
  for (int h = 0; h < RH; ++h) wr1[h] = Wr1[h];

  const int r_local = tid & 31;
  const int s_ii    = tid >> 5;        // 0..7
  const int r = mb * 32 + r_local;
  const int mt_w  = r_local >> 4;
  const int ks_w  = s_ii >> 1;
  const int lane0 = (r_local & 15) + ((s_ii & 1) << 5);

  const float xr0 = x[r * 3 + 0], xr1 = x[r * 3 + 1], xr2 = x[r * 3 + 2];
  float sx[NITER], sy[NITER], sz[NITER];
  #pragma unroll
  for (int it = 0; it < NITER; ++it) {
    const int s = kc * SEND_PER_KC + it * 8 + s_ii;
    sx[it] = x[s * 3 + 0]; sy[it] = x[s * 3 + 1]; sz[it] = x[s * 3 + 2];
  }

  f32x4 accS[4], accV[8];
  #pragma unroll
  for (int i = 0; i < 4; ++i) accS[i] = (f32x4){0.f, 0.f, 0.f, 0.f};
  #pragma unroll
  for (int i = 0; i < 8; ++i) accV[i] = (f32x4){0.f, 0.f, 0.f, 0.f};

  for (int it = 0; it < NITER; ++it) {
    // ---- A generation: silu chain ONCE, two LDS images ----
    {
      const float vx = sx[it] - xr0;
      const float vy = sy[it] - xr1;
      const float vz = sz[it] - xr2;
      const float dd = __builtin_amdgcn_sqrtf(vx * vx + vy * vy + vz * vz);
      const float iv = __builtin_amdgcn_rcpf(dd + 1e-8f);
      float sv[RH];
      #pragma unroll
      for (int h = 0; h < RH; ++h) sv[h] = silu_f(dd * wr1[h]);
      bf16x8_t o0, o1, g0, g1;
      #pragma unroll
      for (int h = 0; h < 8; ++h) {
        o0[h] = f2bf(sv[h]);
        o1[h] = f2bf(sv[h + 8]);
        g0[h] = f2bf(sv[h] * iv);
        g1[h] = f2bf(sv[h + 8] * iv);
      }
      const int off0 = ((ks_w * 2 + mt_w) * 64 + lane0) * 8;
      *(bf16x8_t*)&A_lds[off0]       = o0;
      *(bf16x8_t*)&A_lds[off0 + 128] = o1;   // +16 lanes * 8
      *(bf16x8_t*)&G_lds[off0]       = g0;
      *(bf16x8_t*)&G_lds[off0 + 128] = g1;
    }
    __syncthreads();

    // ---- MFMA: scalar (2 nt) + vector (4 nt) per wave ----
    const int kgb = kc * (SEND_PER_KC / 2) + it * 4;
    #pragma unroll
    for (int ks = 0; ks < 4; ++ks) {
      const bf16x8_t b0 =
          *(const bf16x8_t*)&Bs[((size_t)((kgb + ks) * NT_S + 2 * w) * 64 + lane) * 8];
      const bf16x8_t b1 =
          *(const bf16x8_t*)&Bs[((size_t)((kgb + ks) * NT_S + 2 * w + 1) * 64 + lane) * 8];
      bf16x8_t bv[4];
      #pragma unroll
      for (int j = 0; j < 4; ++j)
        bv[j] = *(const bf16x8_t*)&Bv[((size_t)((kgb + ks) * NT_V + 4 * w + j) * 64 + lane) * 8];
      #pragma unroll
      for (int mt = 0; mt < 2; ++mt) {
        const int aoff = ((ks * 2 + mt) * 64 + lane) * 8;
        const bf16x8_t a  = *(const bf16x8_t*)&A_lds[aoff];
        const bf16x8_t ag = *(const bf16x8_t*)&G_lds[aoff];
        accS[mt * 2 + 0] = __builtin_amdgcn_mfma_f32_16x16x32_bf16(a, b0, accS[mt * 2 + 0], 0, 0, 0);
        accS[mt * 2 + 1] = __builtin_amdgcn_mfma_f32_16x16x32_bf16(a, b1, accS[mt * 2 + 1], 0, 0, 0);
        #pragma unroll
        for (int j = 0; j < 4; ++j)
          accV[mt * 4 + j] = __builtin_amdgcn_mfma_f32_16x16x32_bf16(ag, bv[j], accV[mt * 4 + j], 0, 0, 0);
      }
    }
    __syncthreads();
  }

  // ---- epilogue: write bf16 partials (each element written exactly once) ----
  const int rowq = (lane >> 4) << 2;
  #pragma unroll
  for (int j = 0; j < 2; ++j) {
    const int col = (2 * w + j) * 16 + (lane & 15);
    #pragma unroll
    for (int mt = 0; mt < 2; ++mt) {
      #pragma unroll
      for (int reg = 0; reg < 4; ++reg) {
        const int row = mb * 32 + mt * 16 + rowq + reg;
        Ps[((size_t)kc * NN + row) * FF + col] =
            (unsigned short)f2bf(accS[mt * 2 + j][reg]);
      }
    }
  }
  #pragma unroll
  for (int j = 0; j < 4; ++j) {
    const int col = (4 * w + j) * 16 + (lane & 15);
    #pragma unroll
    for (int mt = 0; mt < 2; ++mt) {
      #pragma unroll
      for (int reg = 0; reg < 4; ++reg) {
        const int row = mb * 32 + mt * 16 + rowq + reg;
        Pv[((size_t)kc * NN + row) * 256 + col] =
            (unsigned short)f2bf(accV[mt * 4 + j][reg]);
      }
    }
  }
}

// ---------------------------------------------------------------------------
// final kernel (R13 verbatim): node1 (bf16 partial reduce) + readout fused.
// ---------------------------------------------------------------------------
__global__ __launch_bounds__(512) void final_kernel(
    const unsigned short* __restrict__ Ps,  // [SPLITK][768][128] bf16
    const unsigned short* __restrict__ Pv,  // [SPLITK][768][256] bf16
    const float* __restrict__ x,
    const float* __restrict__ hs,       // layer-0 output
    const float* __restrict__ hv,       // layer-0 output
    const float* __restrict__ Wss,      // layer-1
    const float* __restrict__ Wvs,      // layer-1
    const float* __restrict__ Wvv,      // layer-1
    const float* __restrict__ Wro_s1,
    const float* __restrict__ Wro_s2,
    const float* __restrict__ Wro_v1,
    const float* __restrict__ Wro_v2,
    float* __restrict__ out)
{
  __shared__ float as_l[FF];
  __shared__ float pvs_l[256];
  __shared__ float av_l[192];
  __shared__ float inv_l[VV];
  __shared__ float hsn[FF];
  __shared__ float hv_l[192];
  __shared__ float red[512];
  __shared__ float red2[384];
  __shared__ float t1[FF];
  __shared__ float tv1[192];
  const int n = blockIdx.x, t = threadIdx.x;

  // fused splitK reduce (bf16 loads)
  if (t < FF) {
    float a = 0.f;
    #pragma unroll
    for (int kc = 0; kc < SPLITK; ++kc)
      a += bf2f(Ps[((size_t)kc * NN + n) * FF + t]);
    as_l[t] = a;
  } else if (t < 384) {
    const int cc = t - 128;
    float a = 0.f;
    #pragma unroll
    for (int kc = 0; kc < SPLITK; ++kc)
      a += bf2f(Pv[((size_t)kc * NN + n) * 256 + cc]);
    pvs_l[cc] = a;
  }
  __syncthreads();

  if (t < VV) {
    const float base = pvs_l[192 + t];
    const float a0 = pvs_l[t]       - x[n * 3 + 0] * base;
    const float a1 = pvs_l[64 + t]  - x[n * 3 + 1] * base;
    const float a2 = pvs_l[128 + t] - x[n * 3 + 2] * base;
    av_l[t * 3 + 0] = a0; av_l[t * 3 + 1] = a1; av_l[t * 3 + 2] = a2;
    inv_l[t] = a0 * a0 + a1 * a1 + a2 * a2;
  }
  __syncthreads();

  // hs partials: 4-way split over K
  {
    const int f = t & 127, part = t >> 7;
    float acc = 0.f;
    const float* wp = Wss + (part * 32) * FF + f;
    #pragma unroll 8
    for (int kk = 0; kk < 32; ++kk) acc += as_l[part * 32 + kk] * wp[kk * FF];
    const float* vp = Wvs + (part * 16) * FF + f;
    #pragma unroll 8
    for (int vv = 0; vv < 16; ++vv) acc += inv_l[part * 16 + vv] * vp[vv * FF];
    red[part * 128 + f] = acc;
  }
  __syncthreads();

  if (t < FF) {
    hsn[t] = silu_f(hs[n * FF + t] + red[t] + red[128 + t] + red[256 + t] + red[384 + t]);
  }
  if (t < 384) {
    const int part = t / 192, j = t - part * 192;
    const int wv = j / 3, d = j - wv * 3;
    float acc = 0.f;
    const float* vp = Wvv + (part * 32) * VV + wv;
    #pragma unroll 8
    for (int v = 0; v < 32; ++v) acc += av_l[(part * 32 + v) * 3 + d] * vp[v * VV];
    red2[part * 192 + j] = acc;
  }
  __syncthreads();

  if (t < 192) hv_l[t] = hv[n * 192 + t] + red2[t] + red2[192 + t];
  __syncthreads();

  // ---- readout, inputs hsn / hv_l ----
  {
    const int f = t & 127, part = t >> 7;
    float acc = 0.f;
    const float* wp = Wro_s1 + (part * 32) * FF + f;
    #pragma unroll 8
    for (int kk = 0; kk < 32; ++kk) acc += hsn[part * 32 + kk] * wp[kk * FF];
    red[part * 128 + f] = acc;
  }
  __syncthreads();
  if (t < FF) t1[t] = silu_f(red[t] + red[128 + t] + red[256 + t] + red[384 + t]);
  if (t < 384) {
    const int part = t / 192, j = t - part * 192;
    const int wv = j / 3, d = j - wv * 3;
    float acc = 0.f;
    const float* vp = Wro_v1 + (part * 32) * VV + wv;
    #pragma unroll 8
    for (int v = 0; v < 32; ++v) acc += hv_l[(part * 32 + v) * 3 + d] * vp[v * VV];
    red2[part * 192 + j] = acc;
  }
  __syncthreads();
  if (t < 192) tv1[t] = red2[t] + red2[192 + t];
  if (t < 256) {
    const int o = t & 63, part = t >> 6;
    float acc = 0.f;
    const float* wp = Wro_s2 + (part * 32) * 64 + o;
    #pragma unroll 8
    for (int f = 0; f < 32; ++f) acc += t1[part * 32 + f] * wp[f * 64];
    red[t] = acc;
  }
  __syncthreads();
  if (t < 64) out[n * 160 + t] = red[t] + red[64 + t] + red[128 + t] + red[192 + t];
  if (t < 192) {
    const int part = t / 96, j = t - part * 96;
    const int w2 = j / 3, d = j - w2 * 3;
    float acc = 0.f;
    const float* vp = Wro_v2 + (part * 32) * 32 + w2;
    #pragma unroll 8
    for (int wv = 0; wv < 32; ++wv) acc += tv1[(part * 32 + wv) * 3 + d] * vp[wv * 32];
    red2[part * 96 + j] = acc;
  }
  __syncthreads();
  if (t < 96) out[n * 160 + 64 + t] = red2[t] + red2[96 + t];
}

// ---------------------------------------------------------------------------
extern "C" void kernel_launch(void* const* d_in, const int* in_sizes, int n_in,
                              void* d_out, int out_size, void* d_ws, size_t ws_size,
                              hipStream_t stream) {
  const float* x      = (const float*)d_in[0];
  const float* embed  = (const float*)d_in[3];
  const float* Wr1    = (const float*)d_in[4];   // [2][1][16]
  const float* Wr2s   = (const float*)d_in[5];   // [2][16][128]
  const float* Wr2v   = (const float*)d_in[6];   // [2][16][64]
  const float* Wsv    = (const float*)d_in[7];   // [2][128][64]
  const float* Wss    = (const float*)d_in[8];   // [2][128][128]
  const float* Wvs    = (const float*)d_in[9];   // [2][64][128]
  const float* Wvv    = (const float*)d_in[10];  // [2][64][64]
  const float* Wro_s1 = (const float*)d_in[11];
  const float* Wro_s2 = (const float*)d_in[12];
  const float* Wro_v1 = (const float*)d_in[13];
  const float* Wro_v2 = (const float*)d_in[14];

  float* ws_f = (float*)d_ws;
  float* hs    = ws_f;                      // 768*128 f32
  float* hsv   = hs + NN * FF;              // 768*64  f32
  float* hv    = hsv + NN * VV;             // 768*192 f32
  unsigned short* Ps = (unsigned short*)(hv + NN * 192);       // 24*768*128 bf16
  unsigned short* Pv = Ps + (size_t)SPLITK * NN * FF;          // 24*768*256 bf16
  unsigned short* Bs = Pv + (size_t)SPLITK * NN * 256;         // 12288*128 bf16
  unsigned short* Bv = Bs + (size_t)12288 * 128;               // 12288*256 bf16
  float* out = (float*)d_out;

  // layer 0 (closed form, register moments) + node0, fused
  layer0_kernel<<<NN, 256, 0, stream>>>(
      x, Wr1, Wr2s, Wr2v, embed, Wsv, Wss, Wvs, Wvv, Wsv + FF * VV,
      hs, hsv, hv);

  // layer 1: B prep -> combined-kind MFMA edge GEMM -> node1+readout fused
  prep_kernel<<<2304, 256, 0, stream>>>(
      hs, hsv, x, Wr2s + RH * FF, Wr2v + RH * VV, Bs, Bv);
  edge_gemm<<<MB_N * SPLITK, 256, 0, stream>>>(
      x, Bs, Bv, Wr1 + RH, Ps, Pv);
  final_kernel<<<NN, 512, 0, stream>>>(
      Ps, Pv, x, hs, hv, Wss + FF * FF, Wvs + VV * FF, Wvv + VV * VV,
      Wro_s1, Wro_s2, Wro_v1, Wro_v2, out);
}